// Round 2
// baseline (1596.515 us; speedup 1.0000x reference)
//
#include <hip/hip_runtime.h>
#include <hip/hip_bf16.h>
#include <math.h>

#define HD 1024
#define ED 512
#define NCLS 10001
#define NNODE 256

__device__ __forceinline__ float sigf(float x){ return 1.f/(1.f+__expf(-x)); }
__device__ __forceinline__ float tanhfast(float x){
  x = fminf(fmaxf(x,-10.f),10.f);
  float e2 = __expf(2.f*x);
  return (e2-1.f)/(e2+1.f);
}

// NOTE: macro params must not be named x/y/z/w — they'd capture member tokens.
#define DOT4(acc_, wv_, xv_) acc_ = fmaf((wv_).x,(xv_).x, fmaf((wv_).y,(xv_).y, fmaf((wv_).z,(xv_).z, fmaf((wv_).w,(xv_).w,(acc_)))))

// transpose-reduce across 64 lanes: input acc[0..63] per lane; output: acc[0] on lane l
// equals sum over lanes of original acc[l]. Static register indices only.
__device__ __forceinline__ void wave_transpose_reduce(float* acc, int lane){
  #pragma unroll
  for (int o = 32; o >= 1; o >>= 1) {
    bool hi = (lane & o) != 0;
    #pragma unroll
    for (int m = 0; m < o; ++m) {
      float s = hi ? acc[m] : acc[m+o];
      float r = __shfl_xor(s, o, 64);
      float kv = hi ? acc[m+o] : acc[m];
      acc[m] = kv + r;
    }
  }
}

// ---------------- transpose W_att -> WT (WT[k][j] = W_att[j][k]) ----------------
__global__ __launch_bounds__(256) void k_tr(const float* __restrict__ W, float* __restrict__ WT){
  __shared__ float tile[32][33];
  int bx = blockIdx.x*32, by = blockIdx.y*32;
  int tx = threadIdx.x & 31, ty = threadIdx.x >> 5;  // 32x8
  #pragma unroll
  for (int yy = ty; yy < 32; yy += 8) tile[yy][tx] = W[(size_t)(by+yy)*HD + bx+tx];
  __syncthreads();
  #pragma unroll
  for (int yy = ty; yy < 32; yy += 8) WT[(size_t)(bx+yy)*HD + by+tx] = tile[tx][yy];
}

// ---------------- root state copy ----------------
__global__ __launch_bounds__(256) void k_root(const float* __restrict__ rH, const float* __restrict__ rC,
                                              float* __restrict__ Hb, float* __restrict__ Cb){
  int t = blockIdx.x*256 + threadIdx.x;
  if (t < HD){ Hb[t]=rH[t]; Cb[t]=rC[t]; }
}

// ---------------- LSTM for one level, slot-grouped ----------------
// grid: (256, chunks, 4 slots), block 256 (4 waves; wave handles unit u = 4 gate rows, 16 nodes)
__global__ __launch_bounds__(256) void k_lstm(
    const float* __restrict__ W_ih, const float* __restrict__ W_hh,
    const float* __restrict__ b_ih, const float* __restrict__ b_hh,
    const float* __restrict__ emb, const int* __restrict__ values,
    float* __restrict__ Hb, float* __restrict__ Cb, const float* __restrict__ Et,
    int s, int e)
{
  const int k    = blockIdx.z;
  const int wv   = threadIdx.x >> 6;
  const int lane = threadIdx.x & 63;
  const int u    = blockIdx.x * 4 + wv;          // 0..1023
  const int i0   = s + k;                         // first node of slot k in level ((s-1)%4==0 for all levels)
  const int nk   = (e - i0 + 3) >> 2;             // nodes of this slot
  const int nbase= blockIdx.y * 16;

  int eof[16], pof[16];
  #pragma unroll
  for (int j=0;j<16;++j){
    int jj = nbase + j; if (jj > nk-1) jj = nk-1;
    int node = i0 + 4*jj;
    int p = (node - 1) >> 2;
    pof[j] = p << 10;
    eof[j] = values[p] << 9;
  }

  float acc[64];
  #pragma unroll
  for (int m=0;m<64;++m) acc[m]=0.f;

  const float* Wi = W_ih + (size_t)k*4096*1536;
  const float* Wh = W_hh + (size_t)k*4096*1024;
  const size_t rA0 = (size_t)(0*1024+u)*1536, rA1 = (size_t)(1*1024+u)*1536,
               rA2 = (size_t)(2*1024+u)*1536, rA3 = (size_t)(3*1024+u)*1536;
  const size_t rB0 = (size_t)(0*1024+u)*1024, rB1 = (size_t)(1*1024+u)*1024,
               rB2 = (size_t)(2*1024+u)*1024, rB3 = (size_t)(3*1024+u)*1024;
  const int l4 = lane*4;

  // phase 1: emb part of x, K in [0,512)
  #pragma unroll
  for (int kk = 0; kk < 512; kk += 256) {
    float4 w0 = *(const float4*)(Wi + rA0 + kk + l4);
    float4 w1 = *(const float4*)(Wi + rA1 + kk + l4);
    float4 w2 = *(const float4*)(Wi + rA2 + kk + l4);
    float4 w3 = *(const float4*)(Wi + rA3 + kk + l4);
    #pragma unroll
    for (int j=0;j<16;++j){
      float4 xv = *(const float4*)(emb + eof[j] + kk + l4);
      DOT4(acc[0*16+j], w0, xv); DOT4(acc[1*16+j], w1, xv);
      DOT4(acc[2*16+j], w2, xv); DOT4(acc[3*16+j], w3, xv);
    }
  }
  // phase 2: parent et part of x, K in [512,1536)
  #pragma unroll
  for (int kk = 512; kk < 1536; kk += 256) {
    float4 w0 = *(const float4*)(Wi + rA0 + kk + l4);
    float4 w1 = *(const float4*)(Wi + rA1 + kk + l4);
    float4 w2 = *(const float4*)(Wi + rA2 + kk + l4);
    float4 w3 = *(const float4*)(Wi + rA3 + kk + l4);
    #pragma unroll
    for (int j=0;j<16;++j){
      float4 xv = *(const float4*)(Et + pof[j] + (kk-512) + l4);
      DOT4(acc[0*16+j], w0, xv); DOT4(acc[1*16+j], w1, xv);
      DOT4(acc[2*16+j], w2, xv); DOT4(acc[3*16+j], w3, xv);
    }
  }
  // phase 3: W_hh @ h_parent
  #pragma unroll
  for (int kk = 0; kk < 1024; kk += 256) {
    float4 w0 = *(const float4*)(Wh + rB0 + kk + l4);
    float4 w1 = *(const float4*)(Wh + rB1 + kk + l4);
    float4 w2 = *(const float4*)(Wh + rB2 + kk + l4);
    float4 w3 = *(const float4*)(Wh + rB3 + kk + l4);
    #pragma unroll
    for (int j=0;j<16;++j){
      float4 xv = *(const float4*)(Hb + pof[j] + kk + l4);
      DOT4(acc[0*16+j], w0, xv); DOT4(acc[1*16+j], w1, xv);
      DOT4(acc[2*16+j], w2, xv); DOT4(acc[3*16+j], w3, xv);
    }
  }

  wave_transpose_reduce(acc, lane);
  // lane = g*16 + j
  int g = lane >> 4, j = lane & 15;
  float val = acc[0] + b_ih[k*4096 + g*1024 + u] + b_hh[k*4096 + g*1024 + u];
  float ig = __shfl(val,      j, 64);
  float fg = __shfl(val, 16 + j, 64);
  float gg = __shfl(val, 32 + j, 64);
  float og = __shfl(val, 48 + j, 64);
  int jj = nbase + j;
  if (lane < 16 && jj < nk) {
    int node = i0 + 4*jj;
    int p = (node-1) >> 2;
    float cp = Cb[(p<<10) + u];
    float c  = sigf(fg)*cp + sigf(ig)*tanhfast(gg);
    float h  = sigf(og)*tanhfast(c);
    Hb[((size_t)node<<10) + u] = h;
    Cb[((size_t)node<<10) + u] = c;
  }
}

// ---------------- generic batched matvec: OUT[n][r] = act(W[r]·[X1[n];X2[n]] + bias[r]) ----------------
// grid: (ceil(R/16), ceil(nn/16)), block 256. K1,K2 multiples of 256 (K2 may be 0).
__global__ __launch_bounds__(256) void k_matvec(
    const float* __restrict__ W, const float* __restrict__ bias,
    const float* __restrict__ X1, int K1,
    const float* __restrict__ X2, int K2,
    float* __restrict__ OUT, int R, int ostride,
    int ns, int nn, int act)
{
  const int wv = threadIdx.x >> 6, lane = threadIdx.x & 63;
  const int rbase = (blockIdx.x*4 + wv)*4;
  const int nbase = blockIdx.y*16;
  const int Kt = K1 + K2;
  const int l4 = lane*4;
  int xo[16];
  #pragma unroll
  for (int j=0;j<16;++j){ int jj=nbase+j; if(jj>nn-1) jj=nn-1; xo[j]=ns+jj; }
  int r0=min(rbase,R-1), r1=min(rbase+1,R-1), r2=min(rbase+2,R-1), r3=min(rbase+3,R-1);
  const float* w0p = W + (size_t)r0*Kt;
  const float* w1p = W + (size_t)r1*Kt;
  const float* w2p = W + (size_t)r2*Kt;
  const float* w3p = W + (size_t)r3*Kt;
  float acc[64];
  #pragma unroll
  for (int m=0;m<64;++m) acc[m]=0.f;

  for (int kk=0; kk<K1; kk+=256){
    float4 w0 = *(const float4*)(w0p + kk + l4);
    float4 w1 = *(const float4*)(w1p + kk + l4);
    float4 w2 = *(const float4*)(w2p + kk + l4);
    float4 w3 = *(const float4*)(w3p + kk + l4);
    #pragma unroll
    for (int j=0;j<16;++j){
      float4 xv = *(const float4*)(X1 + (size_t)xo[j]*K1 + kk + l4);
      DOT4(acc[0*16+j], w0, xv); DOT4(acc[1*16+j], w1, xv);
      DOT4(acc[2*16+j], w2, xv); DOT4(acc[3*16+j], w3, xv);
    }
  }
  if (K2 > 0){
    for (int kk=0; kk<K2; kk+=256){
      float4 w0 = *(const float4*)(w0p + K1 + kk + l4);
      float4 w1 = *(const float4*)(w1p + K1 + kk + l4);
      float4 w2 = *(const float4*)(w2p + K1 + kk + l4);
      float4 w3 = *(const float4*)(w3p + K1 + kk + l4);
      #pragma unroll
      for (int j=0;j<16;++j){
        float4 xv = *(const float4*)(X2 + (size_t)xo[j]*K2 + kk + l4);
        DOT4(acc[0*16+j], w0, xv); DOT4(acc[1*16+j], w1, xv);
        DOT4(acc[2*16+j], w2, xv); DOT4(acc[3*16+j], w3, xv);
      }
    }
  }

  wave_transpose_reduce(acc, lane);
  int g = lane>>4, j = lane&15;
  int r = rbase + g, jj = nbase + j;
  if (r < R && jj < nn) {
    float v = acc[0] + (bias ? bias[r] : 0.f);
    if (act) v = tanhfast(v);
    OUT[(size_t)(ns+jj)*ostride + r] = v;
  }
}

// ---------------- attention per node: logits = ann·t + b_att·h, softmax, ctx = probs@ann ----------------
__global__ __launch_bounds__(256) void k_att2(
    const float* __restrict__ ann, const float* __restrict__ Tb,
    const float* __restrict__ Hb, const float* __restrict__ b_att,
    float* __restrict__ Cx, int ns)
{
  __shared__ float tsh[HD];
  __shared__ float sm[512];
  __shared__ float red[8];
  const int node = ns + blockIdx.x;
  const int tid = threadIdx.x, wv = tid>>6, ln = tid&63;

  float s0p = 0.f;
  for (int c = tid; c < HD; c += 256) {
    tsh[c] = Tb[(size_t)node*HD + c];
    s0p = fmaf(b_att[c], Hb[(size_t)node*HD + c], s0p);
  }
  #pragma unroll
  for (int o=32;o;o>>=1) s0p += __shfl_xor(s0p,o,64);
  if (ln==0) red[wv] = s0p;
  __syncthreads();
  float s0 = red[0]+red[1]+red[2]+red[3];

  // logits (wave per row, K split across lanes as float4)
  const float4* tsh4 = (const float4*)tsh;
  for (int l = wv; l < 512; l += 4) {
    const float4* ar = (const float4*)(ann + (size_t)l*HD);
    float a = 0.f;
    #pragma unroll
    for (int q=0; q<4; ++q) {
      float4 wv4 = ar[q*64 + ln];
      float4 tv4 = tsh4[q*64 + ln];
      DOT4(a, wv4, tv4);
    }
    #pragma unroll
    for (int o=32;o;o>>=1) a += __shfl_xor(a,o,64);
    if (ln==0) sm[l] = a + s0;
  }
  __syncthreads();

  // softmax max
  float m = -1e30f;
  for (int l=tid; l<512; l+=256) m = fmaxf(m, sm[l]);
  #pragma unroll
  for (int o=32;o;o>>=1) m = fmaxf(m, __shfl_xor(m,o,64));
  if (ln==0) red[wv]=m;
  __syncthreads();
  m = fmaxf(fmaxf(red[0],red[1]),fmaxf(red[2],red[3]));
  // exp
  float se = 0.f;
  for (int l=tid; l<512; l+=256){ float ev=__expf(sm[l]-m); sm[l]=ev; se+=ev; }
  __syncthreads();           // red reads done + sm writes visible
  #pragma unroll
  for (int o=32;o;o>>=1) se += __shfl_xor(se,o,64);
  if (ln==0) red[wv]=se;
  __syncthreads();
  float invS = 1.f/(red[0]+red[1]+red[2]+red[3]);

  // ctx: thread owns cols 4*tid..4*tid+3
  float4 a4 = {0.f,0.f,0.f,0.f};
  const float4* ann4 = (const float4*)ann;
  for (int l = 0; l < 512; ++l) {
    float pl = sm[l];
    float4 av = ann4[(size_t)l*256 + tid];
    a4.x = fmaf(pl, av.x, a4.x); a4.y = fmaf(pl, av.y, a4.y);
    a4.z = fmaf(pl, av.z, a4.z); a4.w = fmaf(pl, av.w, a4.w);
  }
  a4.x*=invS; a4.y*=invS; a4.z*=invS; a4.w*=invS;
  *(float4*)(Cx + (size_t)node*HD + tid*4) = a4;
}

// ---------------- loss per node ----------------
__global__ __launch_bounds__(256) void k_loss(const float* __restrict__ Lg,
                                              const int* __restrict__ values,
                                              float* __restrict__ Nl)
{
  __shared__ float red[8];
  const int node = blockIdx.x;
  const int tid = threadIdx.x, wv = tid>>6, ln = tid&63;
  const float* lg = Lg + (size_t)node*NCLS;

  float m = -1e30f;
  for (int i=tid;i<NCLS;i+=256) m = fmaxf(m, lg[i]);
  #pragma unroll
  for (int o=32;o;o>>=1) m = fmaxf(m, __shfl_xor(m,o,64));
  if (ln==0) red[wv]=m;
  __syncthreads();
  m = fmaxf(fmaxf(red[0],red[1]),fmaxf(red[2],red[3]));
  __syncthreads();

  float s = 0.f;
  for (int i=tid;i<NCLS;i+=256) s += __expf(lg[i]-m);
  #pragma unroll
  for (int o=32;o;o>>=1) s += __shfl_xor(s,o,64);
  if (ln==0) red[wv]=s;
  __syncthreads();
  s = red[0]+red[1]+red[2]+red[3];
  __syncthreads();
  float invs = 1.f/s;

  float q = 0.f;
  for (int i=tid;i<NCLS;i+=256) q += __expf(__expf(lg[i]-m)*invs);
  #pragma unroll
  for (int o=32;o;o>>=1) q += __shfl_xor(q,o,64);
  if (ln==0) red[wv]=q;
  __syncthreads();
  if (tid==0) {
    float qq = red[0]+red[1]+red[2]+red[3];
    int v = values[node];
    float pv = __expf(lg[v]-m)*invs;
    float nl = __logf(qq) - pv;
    if (v == NCLS-1) nl *= 0.2f;
    Nl[node] = nl;
  }
}

__global__ __launch_bounds__(256) void k_final(const float* __restrict__ Nl, float* __restrict__ out){
  __shared__ float red[8];
  int tid = threadIdx.x, wv = tid>>6, ln = tid&63;
  float s = Nl[tid];
  #pragma unroll
  for (int o=32;o;o>>=1) s += __shfl_xor(s,o,64);
  if (ln==0) red[wv]=s;
  __syncthreads();
  if (tid==0) out[0] = red[0]+red[1]+red[2]+red[3];
}

extern "C" void kernel_launch(void* const* d_in, const int* in_sizes, int n_in,
                              void* d_out, int out_size, void* d_ws, size_t ws_size,
                              hipStream_t stream)
{
  const float* rootH = (const float*)d_in[0];
  const float* rootC = (const float*)d_in[1];
  const float* ann   = (const float*)d_in[2];
  const int*   values= (const int*)d_in[3];
  const float* emb   = (const float*)d_in[6];
  const float* W_ih  = (const float*)d_in[7];
  const float* W_hh  = (const float*)d_in[8];
  const float* b_ih  = (const float*)d_in[9];
  const float* b_hh  = (const float*)d_in[10];
  const float* W_att = (const float*)d_in[11];
  const float* b_att = (const float*)d_in[12];
  const float* W_pre = (const float*)d_in[13];
  const float* b_pre = (const float*)d_in[14];
  const float* W_out = (const float*)d_in[15];
  const float* b_out = (const float*)d_in[16];

  float* ws = (float*)d_ws;
  float* WT = ws;  ws += 1024*1024;
  float* Hb = ws;  ws += 256*1024;
  float* Cb = ws;  ws += 256*1024;
  float* Et = ws;  ws += 256*1024;
  float* Tb = ws;  ws += 256*1024;
  float* Cx = ws;  ws += 256*1024;
  float* Lg = ws;  ws += (size_t)256*NCLS;
  float* Nl = ws;  ws += 256;

  k_tr  <<<dim3(32,32), 256, 0, stream>>>(W_att, WT);
  k_root<<<4,           256, 0, stream>>>(rootH, rootC, Hb, Cb);

  const int LS[6] = {0,1,5,21,85,256};
  for (int lev=0; lev<5; ++lev){
    int s=LS[lev], e=LS[lev+1], n=e-s;
    if (lev>0){
      int nkmax = (n+3)/4;
      int chunks = (nkmax+15)/16;
      k_lstm<<<dim3(256,chunks,4),256,0,stream>>>(W_ih,W_hh,b_ih,b_hh,emb,values,Hb,Cb,Et,s,e);
    }
    int nch = (n+15)/16;
    k_matvec<<<dim3(64,nch),256,0,stream>>>(WT,   nullptr, Hb,1024, nullptr,0,    Tb,1024,1024, s,n,0);
    k_att2  <<<n,          256,0,stream>>>(ann, Tb, Hb, b_att, Cx, s);
    k_matvec<<<dim3(64,nch),256,0,stream>>>(W_pre, b_pre,  Hb,1024, Cx,1024,      Et,1024,1024, s,n,1);
  }
  k_matvec<<<dim3(626,16),256,0,stream>>>(W_out, b_out, Et,1024, nullptr,0, Lg,NCLS,NCLS, 0,256,0);
  k_loss <<<256,256,0,stream>>>(Lg, values, Nl);
  k_final<<<1,  256,0,stream>>>(Nl, (float*)d_out);
}

// Round 3
// 1325.838 us; speedup vs baseline: 1.2042x; 1.2042x over previous
//
#include <hip/hip_runtime.h>
#include <hip/hip_bf16.h>
#include <math.h>

#define HD 1024
#define NCLS 10001

typedef short s16x8 __attribute__((ext_vector_type(8)));
typedef float f32x4 __attribute__((ext_vector_type(4)));
#define MFMA16(a_, b_, c_) __builtin_amdgcn_mfma_f32_16x16x32_bf16((a_), (b_), (c_), 0, 0, 0)

__device__ __forceinline__ float sigf(float x){ return 1.f/(1.f+__expf(-x)); }
__device__ __forceinline__ float tanhfast(float x){
  x = fminf(fmaxf(x,-10.f),10.f);
  float e2 = __expf(2.f*x);
  return (e2-1.f)/(e2+1.f);
}
__device__ __forceinline__ unsigned short f2bf(float f){
  unsigned int u = __float_as_uint(f);
  u += 0x7FFF + ((u >> 16) & 1);          // round-to-nearest-even
  return (unsigned short)(u >> 16);
}

#define DOT4(acc_, wv_, xv_) acc_ = fmaf((wv_).x,(xv_).x, fmaf((wv_).y,(xv_).y, fmaf((wv_).z,(xv_).z, fmaf((wv_).w,(xv_).w,(acc_)))))

// ---------------- transpose W_att -> WT fp32 (WT[k][j] = W_att[j][k]) ----------------
__global__ __launch_bounds__(256) void k_tr(const float* __restrict__ W, float* __restrict__ WT){
  __shared__ float tile[32][33];
  int bx = blockIdx.x*32, by = blockIdx.y*32;
  int tx = threadIdx.x & 31, ty = threadIdx.x >> 5;
  #pragma unroll
  for (int yy = ty; yy < 32; yy += 8) tile[yy][tx] = W[(size_t)(by+yy)*HD + bx+tx];
  __syncthreads();
  #pragma unroll
  for (int yy = ty; yy < 32; yy += 8) WT[(size_t)(bx+yy)*HD + by+tx] = tile[tx][yy];
}

// ---------------- root state ----------------
__global__ __launch_bounds__(256) void k_root(const float* __restrict__ rH, const float* __restrict__ rC,
                                              float* __restrict__ Hb, float* __restrict__ Cb,
                                              unsigned short* __restrict__ Hbf){
  int t = blockIdx.x*256 + threadIdx.x;
  if (t < HD){ Hb[t]=rH[t]; Cb[t]=rC[t]; Hbf[t]=f2bf(rH[t]); }
}

// ---------------- X assembly for LSTM level: X[slot][j] = [emb(values[p]) | Et_bf[p] | bf(Hb[p])] ----------------
__global__ __launch_bounds__(256) void k_xasm(const float* __restrict__ emb, const int* __restrict__ values,
                                              const unsigned short* __restrict__ Etb, const float* __restrict__ Hb,
                                              unsigned short* __restrict__ X, int s, int e){
  int i = s + blockIdx.x;
  if (i >= e) return;
  int slot = (i - s) & 3, j = (i - s) >> 2;
  int p = (i - 1) >> 2;
  unsigned short* xr = X + ((size_t)slot*48 + j) * 2560;
  int tid = threadIdx.x;
  const float* er = emb + (size_t)values[p] * 512;
  for (int c = tid; c < 512;  c += 256) xr[c]        = f2bf(er[c]);
  const unsigned short* et = Etb + (size_t)p * 1024;
  for (int c = tid; c < 1024; c += 256) xr[512 + c]  = et[c];
  const float* hp = Hb + (size_t)p * 1024;
  for (int c = tid; c < 1024; c += 256) xr[1536 + c] = f2bf(hp[c]);
}

// ---------------- generic MFMA GEMM: C[m][n] = act( sum_k A[m][k]*B[n][k] + bias[n] ) ----------------
// A bf16 [M x K] row-major (row stride K). B fp32 rows, split B1 (K1) | B2 (K2) along k, cvt on the fly.
// Block = 4 waves; wave covers 16 cols x MT*16 rows. grid.x covers N/64; grid.z optional (LSTM slots).
template<int MT>
__global__ __launch_bounds__(256) void k_gemm(
    const unsigned short* __restrict__ A,
    const float* __restrict__ B1, int K1,
    const float* __restrict__ B2, int K2,
    const float* __restrict__ bias,
    float* __restrict__ Cf, unsigned short* __restrict__ Cb16,
    int ostride, int N, int Mbase, int lstm_mode,
    int aZ, int b1Z, int b2Z, int cZ, int tanh_flag)
{
  const int z = blockIdx.z;
  const int M = lstm_mode ? ((Mbase - z + 3) >> 2) : Mbase;
  const unsigned short* Az = A + (size_t)z * aZ;
  const float* B1z = B1 + (size_t)z * b1Z;
  const float* B2z = B2 ? (B2 + (size_t)z * b2Z) : nullptr;
  const int K = K1 + K2;
  const int wv = threadIdx.x >> 6, lane = threadIdx.x & 63;
  const int col = (blockIdx.x*4 + wv)*16 + (lane & 15);
  const int colc = min(col, N-1);
  const int khalf = (lane >> 4) * 8;

  f32x4 acc[MT];
  #pragma unroll
  for (int m = 0; m < MT; ++m) acc[m] = (f32x4){0.f,0.f,0.f,0.f};
  int arow[MT];
  #pragma unroll
  for (int m = 0; m < MT; ++m) arow[m] = min(m*16 + (lane & 15), M-1);

  for (int kk = 0; kk < K; kk += 32) {
    int kb = kk + khalf;
    const float* bp = (kb < K1) ? (B1z + (size_t)colc * K1 + kb)
                                : (B2z + (size_t)colc * K2 + (kb - K1));
    float4 b0 = *(const float4*)bp;
    float4 b1 = *(const float4*)(bp + 4);
    s16x8 bf;
    bf[0]=(short)f2bf(b0.x); bf[1]=(short)f2bf(b0.y); bf[2]=(short)f2bf(b0.z); bf[3]=(short)f2bf(b0.w);
    bf[4]=(short)f2bf(b1.x); bf[5]=(short)f2bf(b1.y); bf[6]=(short)f2bf(b1.z); bf[7]=(short)f2bf(b1.w);
    #pragma unroll
    for (int m = 0; m < MT; ++m) {
      s16x8 af = *(const s16x8*)(Az + (size_t)arow[m] * K + kb);
      acc[m] = MFMA16(af, bf, acc[m]);
    }
  }

  const int r0 = (lane >> 4) * 4;
  #pragma unroll
  for (int m = 0; m < MT; ++m) {
    #pragma unroll
    for (int q = 0; q < 4; ++q) {
      int row = m*16 + r0 + q;
      if (row < M && col < N) {
        float v = acc[m][q] + (bias ? bias[col] : 0.f);
        if (tanh_flag) v = tanhfast(v);
        size_t off = (size_t)row * ostride + col + (size_t)z * cZ;
        if (Cb16) Cb16[off] = f2bf(v); else Cf[off] = v;
      }
    }
  }
}

// ---------------- LSTM epilogue: gates -> h,c ----------------
__global__ __launch_bounds__(256) void k_epi(const float* __restrict__ G,
                                             const float* __restrict__ b_ih, const float* __restrict__ b_hh,
                                             float* __restrict__ Hb, float* __restrict__ Cb,
                                             unsigned short* __restrict__ Hbf, int s, int e){
  int i = s + blockIdx.x;
  if (i >= e) return;
  int slot = (i - s) & 3, j = (i - s) >> 2;
  int p = (i - 1) >> 2;
  const float* g  = G + ((size_t)slot*48 + j) * 4096;
  const float* bi = b_ih + (size_t)slot*4096;
  const float* bh = b_hh + (size_t)slot*4096;
  for (int u = threadIdx.x; u < 1024; u += 256) {
    float ig = g[u]      + bi[u]      + bh[u];
    float fg = g[1024+u] + bi[1024+u] + bh[1024+u];
    float gg = g[2048+u] + bi[2048+u] + bh[2048+u];
    float og = g[3072+u] + bi[3072+u] + bh[3072+u];
    float cp = Cb[(size_t)p*1024 + u];
    float c  = sigf(fg)*cp + sigf(ig)*tanhfast(gg);
    float h  = sigf(og)*tanhfast(c);
    Hb [(size_t)i*1024+u] = h;
    Cb [(size_t)i*1024+u] = c;
    Hbf[(size_t)i*1024+u] = f2bf(h);
  }
}

// ---------------- attention per node: logits = ann·t + b_att·h, softmax, ctx; writes XP=[bf(h)|bf(ctx)] ----------------
__global__ __launch_bounds__(256) void k_att2(
    const float* __restrict__ ann, const float* __restrict__ Tb,
    const float* __restrict__ Hb, const float* __restrict__ b_att,
    unsigned short* __restrict__ XP, int ns)
{
  __shared__ float tsh[HD];
  __shared__ float sm[512];
  __shared__ float red[8];
  const int node = ns + blockIdx.x;
  const int tid = threadIdx.x, wv = tid>>6, ln = tid&63;

  float s0p = 0.f;
  for (int c = tid; c < HD; c += 256) {
    tsh[c] = Tb[(size_t)node*HD + c];
    float h = Hb[(size_t)node*HD + c];
    s0p = fmaf(b_att[c], h, s0p);
    XP[(size_t)node*2048 + c] = f2bf(h);
  }
  #pragma unroll
  for (int o=32;o;o>>=1) s0p += __shfl_xor(s0p,o,64);
  if (ln==0) red[wv] = s0p;
  __syncthreads();
  float s0 = red[0]+red[1]+red[2]+red[3];

  const float4* tsh4 = (const float4*)tsh;
  for (int l = wv; l < 512; l += 4) {
    const float4* ar = (const float4*)(ann + (size_t)l*HD);
    float a = 0.f;
    #pragma unroll
    for (int q=0; q<4; ++q) {
      float4 wv4 = ar[q*64 + ln];
      float4 tv4 = tsh4[q*64 + ln];
      DOT4(a, wv4, tv4);
    }
    #pragma unroll
    for (int o=32;o;o>>=1) a += __shfl_xor(a,o,64);
    if (ln==0) sm[l] = a + s0;
  }
  __syncthreads();

  float m = -1e30f;
  for (int l=tid; l<512; l+=256) m = fmaxf(m, sm[l]);
  #pragma unroll
  for (int o=32;o;o>>=1) m = fmaxf(m, __shfl_xor(m,o,64));
  if (ln==0) red[wv]=m;
  __syncthreads();
  m = fmaxf(fmaxf(red[0],red[1]),fmaxf(red[2],red[3]));
  float se = 0.f;
  for (int l=tid; l<512; l+=256){ float ev=__expf(sm[l]-m); sm[l]=ev; se+=ev; }
  __syncthreads();
  #pragma unroll
  for (int o=32;o;o>>=1) se += __shfl_xor(se,o,64);
  if (ln==0) red[wv]=se;
  __syncthreads();
  float invS = 1.f/(red[0]+red[1]+red[2]+red[3]);

  float4 a4 = {0.f,0.f,0.f,0.f};
  const float4* ann4 = (const float4*)ann;
  for (int l = 0; l < 512; ++l) {
    float pl = sm[l];
    float4 av = ann4[(size_t)l*256 + tid];
    a4.x = fmaf(pl, av.x, a4.x); a4.y = fmaf(pl, av.y, a4.y);
    a4.z = fmaf(pl, av.z, a4.z); a4.w = fmaf(pl, av.w, a4.w);
  }
  unsigned short* xp = XP + (size_t)node*2048 + 1024 + tid*4;
  xp[0]=f2bf(a4.x*invS); xp[1]=f2bf(a4.y*invS); xp[2]=f2bf(a4.z*invS); xp[3]=f2bf(a4.w*invS);
}

// ---------------- loss per node ----------------
__global__ __launch_bounds__(256) void k_loss(const float* __restrict__ Lg,
                                              const int* __restrict__ values,
                                              float* __restrict__ Nl)
{
  __shared__ float red[8];
  const int node = blockIdx.x;
  const int tid = threadIdx.x, wv = tid>>6, ln = tid&63;
  const float* lg = Lg + (size_t)node*NCLS;

  float m = -1e30f;
  for (int i=tid;i<NCLS;i+=256) m = fmaxf(m, lg[i]);
  #pragma unroll
  for (int o=32;o;o>>=1) m = fmaxf(m, __shfl_xor(m,o,64));
  if (ln==0) red[wv]=m;
  __syncthreads();
  m = fmaxf(fmaxf(red[0],red[1]),fmaxf(red[2],red[3]));
  __syncthreads();

  float s = 0.f;
  for (int i=tid;i<NCLS;i+=256) s += __expf(lg[i]-m);
  #pragma unroll
  for (int o=32;o;o>>=1) s += __shfl_xor(s,o,64);
  if (ln==0) red[wv]=s;
  __syncthreads();
  s = red[0]+red[1]+red[2]+red[3];
  __syncthreads();
  float invs = 1.f/s;

  float q = 0.f;
  for (int i=tid;i<NCLS;i+=256) q += __expf(__expf(lg[i]-m)*invs);
  #pragma unroll
  for (int o=32;o;o>>=1) q += __shfl_xor(q,o,64);
  if (ln==0) red[wv]=q;
  __syncthreads();
  if (tid==0) {
    float qq = red[0]+red[1]+red[2]+red[3];
    int v = values[node];
    float pv = __expf(lg[v]-m)*invs;
    float nl = __logf(qq) - pv;
    if (v == NCLS-1) nl *= 0.2f;
    Nl[node] = nl;
  }
}

__global__ __launch_bounds__(256) void k_final(const float* __restrict__ Nl, float* __restrict__ out){
  __shared__ float red[8];
  int tid = threadIdx.x, wv = tid>>6, ln = tid&63;
  float s = Nl[tid];
  #pragma unroll
  for (int o=32;o;o>>=1) s += __shfl_xor(s,o,64);
  if (ln==0) red[wv]=s;
  __syncthreads();
  if (tid==0) out[0] = red[0]+red[1]+red[2]+red[3];
}

static inline void gemm(hipStream_t st, int MT, dim3 grid,
    const unsigned short* A, const float* B1, int K1, const float* B2, int K2,
    const float* bias, float* Cf, unsigned short* Cb16, int ostride, int N,
    int Mbase, int lstm, int aZ, int b1Z, int b2Z, int cZ, int tanhf)
{
  #define GCASE(MTv) k_gemm<MTv><<<grid, 256, 0, st>>>(A,B1,K1,B2,K2,bias,Cf,Cb16,ostride,N,Mbase,lstm,aZ,b1Z,b2Z,cZ,tanhf)
  switch(MT){
    case 1:  GCASE(1);  break;
    case 3:  GCASE(3);  break;
    case 4:  GCASE(4);  break;
    case 11: GCASE(11); break;
    default: GCASE(16); break;
  }
  #undef GCASE
}

extern "C" void kernel_launch(void* const* d_in, const int* in_sizes, int n_in,
                              void* d_out, int out_size, void* d_ws, size_t ws_size,
                              hipStream_t stream)
{
  const float* rootH = (const float*)d_in[0];
  const float* rootC = (const float*)d_in[1];
  const float* ann   = (const float*)d_in[2];
  const int*   values= (const int*)d_in[3];
  const float* emb   = (const float*)d_in[6];
  const float* W_ih  = (const float*)d_in[7];
  const float* W_hh  = (const float*)d_in[8];
  const float* b_ih  = (const float*)d_in[9];
  const float* b_hh  = (const float*)d_in[10];
  const float* W_att = (const float*)d_in[11];
  const float* b_att = (const float*)d_in[12];
  const float* W_pre = (const float*)d_in[13];
  const float* b_pre = (const float*)d_in[14];
  const float* W_out = (const float*)d_in[15];
  const float* b_out = (const float*)d_in[16];

  float* ws = (float*)d_ws;
  float* WT = ws;  ws += 1024*1024;           // fp32 W_att^T
  float* Hb = ws;  ws += 256*1024;            // fp32 h
  float* Cb = ws;  ws += 256*1024;            // fp32 c
  float* Tb = ws;  ws += 256*1024;            // fp32 t = W_att^T h
  float* G  = ws;  ws += 4*48*4096;           // fp32 LSTM gates per slot
  float* Lg = ws;  ws += (size_t)256*NCLS;    // fp32 logits
  float* Nl = ws;  ws += 256;
  unsigned short* Hbf = (unsigned short*)ws;  // bf16 h            [256][1024]
  unsigned short* Etb = Hbf + 256*1024;       // bf16 et           [256][1024]
  unsigned short* XP  = Etb + 256*1024;       // bf16 [h|ctx]      [256][2048]
  unsigned short* Xb  = XP  + 256*2048;       // bf16 lstm input   [4][48][2560]

  k_tr  <<<dim3(32,32), 256, 0, stream>>>(W_att, WT);
  k_root<<<4,           256, 0, stream>>>(rootH, rootC, Hb, Cb, Hbf);

  const int LS[6] = {0,1,5,21,85,256};
  // level 0 (root): attention + pre
  gemm(stream, 1, dim3(16,1,1), Hbf, WT, 1024, nullptr,0, nullptr, Tb, nullptr, 1024, 1024, 1, 0, 0,0,0,0, 0);
  k_att2<<<1,256,0,stream>>>(ann, Tb, Hb, b_att, XP, 0);
  gemm(stream, 1, dim3(16,1,1), XP, W_pre, 2048, nullptr,0, b_pre, nullptr, Etb, 1024, 1024, 1, 0, 0,0,0,0, 1);

  for (int lev=1; lev<5; ++lev){
    int s=LS[lev], e=LS[lev+1], n=e-s;
    k_xasm<<<n,256,0,stream>>>(emb, values, Etb, Hb, Xb, s, e);
    int mtl = (lev==4) ? 3 : 1;
    gemm(stream, mtl, dim3(64,1,4), Xb, W_ih, 1536, W_hh, 1024, nullptr, G, nullptr,
         4096, 4096, n, 1, 48*2560, 4096*1536, 4096*1024, 48*4096, 0);
    k_epi<<<n,256,0,stream>>>(G, b_ih, b_hh, Hb, Cb, Hbf, s, e);
    int mtn = (n+15)/16;
    gemm(stream, mtn, dim3(16,1,1), Hbf + (size_t)s*1024, WT, 1024, nullptr,0, nullptr,
         Tb + (size_t)s*1024, nullptr, 1024, 1024, n, 0, 0,0,0,0, 0);
    k_att2<<<n,256,0,stream>>>(ann, Tb, Hb, b_att, XP, s);
    gemm(stream, mtn, dim3(16,1,1), XP + (size_t)s*2048, W_pre, 2048, nullptr,0, b_pre, nullptr,
         Etb + (size_t)s*1024, 1024, 1024, n, 0, 0,0,0,0, 1);
  }

  gemm(stream, 16, dim3(157,1,1), Etb, W_out, 1024, nullptr,0, b_out, Lg, nullptr,
       10001, 10001, 256, 0, 0,0,0,0, 0);
  k_loss <<<256,256,0,stream>>>(Lg, values, Nl);
  k_final<<<1,  256,0,stream>>>(Nl, (float*)d_out);
}

// Round 4
// 908.008 us; speedup vs baseline: 1.7583x; 1.4602x over previous
//
#include <hip/hip_runtime.h>
#include <hip/hip_bf16.h>
#include <math.h>

#define HD 1024
#define NCLS 10001

typedef short s16x8 __attribute__((ext_vector_type(8)));
typedef float f32x4 __attribute__((ext_vector_type(4)));
#define MFMA16(a_, b_, c_) __builtin_amdgcn_mfma_f32_16x16x32_bf16((a_), (b_), (c_), 0, 0, 0)

__device__ __forceinline__ float sigf(float x){ return 1.f/(1.f+__expf(-x)); }
__device__ __forceinline__ float tanhfast(float x){
  x = fminf(fmaxf(x,-10.f),10.f);
  float e2 = __expf(2.f*x);
  return (e2-1.f)/(e2+1.f);
}
__device__ __forceinline__ unsigned short f2bf(float f){
  unsigned int u = __float_as_uint(f);
  u += 0x7FFF + ((u >> 16) & 1);          // round-to-nearest-even
  return (unsigned short)(u >> 16);
}

#define DOT4(acc_, wv_, xv_) acc_ = fmaf((wv_).x,(xv_).x, fmaf((wv_).y,(xv_).y, fmaf((wv_).z,(xv_).z, fmaf((wv_).w,(xv_).w,(acc_)))))

// ---------------- transpose W_att -> WT fp32 ----------------
__global__ __launch_bounds__(256) void k_tr(const float* __restrict__ W, float* __restrict__ WT){
  __shared__ float tile[32][33];
  int bx = blockIdx.x*32, by = blockIdx.y*32;
  int tx = threadIdx.x & 31, ty = threadIdx.x >> 5;
  #pragma unroll
  for (int yy = ty; yy < 32; yy += 8) tile[yy][tx] = W[(size_t)(by+yy)*HD + bx+tx];
  __syncthreads();
  #pragma unroll
  for (int yy = ty; yy < 32; yy += 8) WT[(size_t)(bx+yy)*HD + by+tx] = tile[tx][yy];
}

// ---------------- root state ----------------
__global__ __launch_bounds__(256) void k_root(const float* __restrict__ rH, const float* __restrict__ rC,
                                              float* __restrict__ Hb, float* __restrict__ Cb,
                                              unsigned short* __restrict__ Hbf){
  int t = blockIdx.x*256 + threadIdx.x;
  if (t < HD){ Hb[t]=rH[t]; Cb[t]=rC[t]; Hbf[t]=f2bf(rH[t]); }
}

// ---------------- X assembly for LSTM level ----------------
__global__ __launch_bounds__(256) void k_xasm(const float* __restrict__ emb, const int* __restrict__ values,
                                              const unsigned short* __restrict__ Etb, const float* __restrict__ Hb,
                                              unsigned short* __restrict__ X, int s, int e){
  int i = s + blockIdx.x;
  if (i >= e) return;
  int slot = (i - s) & 3, j = (i - s) >> 2;
  int p = (i - 1) >> 2;
  unsigned short* xr = X + ((size_t)slot*48 + j) * 2560;
  int tid = threadIdx.x;
  const float* er = emb + (size_t)values[p] * 512;
  for (int c = tid; c < 512;  c += 256) xr[c]        = f2bf(er[c]);
  const unsigned short* et = Etb + (size_t)p * 1024;
  for (int c = tid; c < 1024; c += 256) xr[512 + c]  = et[c];
  const float* hp = Hb + (size_t)p * 1024;
  for (int c = tid; c < 1024; c += 256) xr[1536 + c] = f2bf(hp[c]);
}

// ---------------- MFMA GEMM (full-K; used for LSTM + W_out) ----------------
template<int MT>
__global__ __launch_bounds__(256) void k_gemm(
    const unsigned short* __restrict__ A,
    const float* __restrict__ B1, int K1,
    const float* __restrict__ B2, int K2,
    const float* __restrict__ bias,
    float* __restrict__ Cf, unsigned short* __restrict__ Cb16,
    int ostride, int N, int Mbase, int lstm_mode,
    int aZ, int b1Z, int b2Z, int cZ, int tanh_flag)
{
  const int z = blockIdx.z;
  const int M = lstm_mode ? ((Mbase - z + 3) >> 2) : Mbase;
  const unsigned short* Az = A + (size_t)z * aZ;
  const float* B1z = B1 + (size_t)z * b1Z;
  const float* B2z = B2 ? (B2 + (size_t)z * b2Z) : nullptr;
  const int K = K1 + K2;
  const int wv = threadIdx.x >> 6, lane = threadIdx.x & 63;
  const int col = (blockIdx.x*4 + wv)*16 + (lane & 15);
  const int colc = min(col, N-1);
  const int khalf = (lane >> 4) * 8;

  f32x4 acc[MT];
  #pragma unroll
  for (int m = 0; m < MT; ++m) acc[m] = (f32x4){0.f,0.f,0.f,0.f};
  int arow[MT];
  #pragma unroll
  for (int m = 0; m < MT; ++m) arow[m] = min(m*16 + (lane & 15), M-1);

  for (int kk = 0; kk < K; kk += 32) {
    int kb = kk + khalf;
    const float* bp = (kb < K1) ? (B1z + (size_t)colc * K1 + kb)
                                : (B2z + (size_t)colc * K2 + (kb - K1));
    float4 b0 = *(const float4*)bp;
    float4 b1 = *(const float4*)(bp + 4);
    s16x8 bf;
    bf[0]=(short)f2bf(b0.x); bf[1]=(short)f2bf(b0.y); bf[2]=(short)f2bf(b0.z); bf[3]=(short)f2bf(b0.w);
    bf[4]=(short)f2bf(b1.x); bf[5]=(short)f2bf(b1.y); bf[6]=(short)f2bf(b1.z); bf[7]=(short)f2bf(b1.w);
    #pragma unroll
    for (int m = 0; m < MT; ++m) {
      s16x8 af = *(const s16x8*)(Az + (size_t)arow[m] * K + kb);
      acc[m] = MFMA16(af, bf, acc[m]);
    }
  }

  const int r0 = (lane >> 4) * 4;
  #pragma unroll
  for (int m = 0; m < MT; ++m) {
    #pragma unroll
    for (int q = 0; q < 4; ++q) {
      int row = m*16 + r0 + q;
      if (row < M && col < N) {
        float v = acc[m][q] + (bias ? bias[col] : 0.f);
        if (tanh_flag) v = tanhfast(v);
        size_t off = (size_t)row * ostride + col + (size_t)z * cZ;
        if (Cb16) Cb16[off] = f2bf(v); else Cf[off] = v;
      }
    }
  }
}

// ---------------- split-K MFMA GEMM: partials P[ks][M][N], no bias ----------------
// grid (N/64, KS); each block handles K-chunk of 128.
template<int MT>
__global__ __launch_bounds__(256) void k_gemm_sk(
    const unsigned short* __restrict__ A,
    const float* __restrict__ B1, int K1,
    const float* __restrict__ B2, int K2,
    float* __restrict__ P, int N, int M)
{
  const int K = K1 + K2;
  const int ks = blockIdx.y;
  const int k0 = ks * 128;
  const int wv = threadIdx.x >> 6, lane = threadIdx.x & 63;
  const int col = (blockIdx.x*4 + wv)*16 + (lane & 15);
  const int colc = min(col, N-1);
  const int khalf = (lane >> 4) * 8;

  f32x4 acc[MT];
  #pragma unroll
  for (int m = 0; m < MT; ++m) acc[m] = (f32x4){0.f,0.f,0.f,0.f};
  int arow[MT];
  #pragma unroll
  for (int m = 0; m < MT; ++m) arow[m] = min(m*16 + (lane & 15), M-1);

  #pragma unroll
  for (int kk = 0; kk < 128; kk += 32) {
    int kb = k0 + kk + khalf;
    const float* bp = (kb < K1) ? (B1 + (size_t)colc * K1 + kb)
                                : (B2 + (size_t)colc * K2 + (kb - K1));
    float4 b0 = *(const float4*)bp;
    float4 b1 = *(const float4*)(bp + 4);
    s16x8 bf;
    bf[0]=(short)f2bf(b0.x); bf[1]=(short)f2bf(b0.y); bf[2]=(short)f2bf(b0.z); bf[3]=(short)f2bf(b0.w);
    bf[4]=(short)f2bf(b1.x); bf[5]=(short)f2bf(b1.y); bf[6]=(short)f2bf(b1.z); bf[7]=(short)f2bf(b1.w);
    #pragma unroll
    for (int m = 0; m < MT; ++m) {
      s16x8 af = *(const s16x8*)(A + (size_t)arow[m] * K + kb);
      acc[m] = MFMA16(af, bf, acc[m]);
    }
  }

  const int r0 = (lane >> 4) * 4;
  #pragma unroll
  for (int m = 0; m < MT; ++m) {
    #pragma unroll
    for (int q = 0; q < 4; ++q) {
      int row = m*16 + r0 + q;
      if (row < M && col < N)
        P[((size_t)ks*M + row)*N + col] = acc[m][q];
    }
  }
}

// ---------------- split-K reduction: out = act(sum_ks P + bias) ----------------
__global__ __launch_bounds__(256) void k_red(const float* __restrict__ P, int KS, int M, int N,
                                             const float* __restrict__ bias, int tanh_flag,
                                             float* __restrict__ Cf, unsigned short* __restrict__ Cb16,
                                             int ostride)
{
  int idx = blockIdx.x*256 + threadIdx.x;
  if (idx >= M*N) return;
  int row = idx / N, col = idx - row*N;
  float s = bias ? bias[col] : 0.f;
  for (int ks = 0; ks < KS; ++ks) s += P[((size_t)ks*M + row)*N + col];
  if (tanh_flag) s = tanhfast(s);
  if (Cb16) Cb16[(size_t)row*ostride + col] = f2bf(s);
  else      Cf  [(size_t)row*ostride + col] = s;
}

// ---------------- LSTM epilogue ----------------
__global__ __launch_bounds__(256) void k_epi(const float* __restrict__ G,
                                             const float* __restrict__ b_ih, const float* __restrict__ b_hh,
                                             float* __restrict__ Hb, float* __restrict__ Cb,
                                             unsigned short* __restrict__ Hbf, int s, int e){
  int i = s + blockIdx.x;
  if (i >= e) return;
  int slot = (i - s) & 3, j = (i - s) >> 2;
  int p = (i - 1) >> 2;
  const float* g  = G + ((size_t)slot*48 + j) * 4096;
  const float* bi = b_ih + (size_t)slot*4096;
  const float* bh = b_hh + (size_t)slot*4096;
  for (int u = threadIdx.x; u < 1024; u += 256) {
    float ig = g[u]      + bi[u]      + bh[u];
    float fg = g[1024+u] + bi[1024+u] + bh[1024+u];
    float gg = g[2048+u] + bi[2048+u] + bh[2048+u];
    float og = g[3072+u] + bi[3072+u] + bh[3072+u];
    float cp = Cb[(size_t)p*1024 + u];
    float c  = sigf(fg)*cp + sigf(ig)*tanhfast(gg);
    float h  = sigf(og)*tanhfast(c);
    Hb [(size_t)i*1024+u] = h;
    Cb [(size_t)i*1024+u] = c;
    Hbf[(size_t)i*1024+u] = f2bf(h);
  }
}

// ---------------- attention per node ----------------
__global__ __launch_bounds__(256) void k_att2(
    const float* __restrict__ ann, const float* __restrict__ Tb,
    const float* __restrict__ Hb, const float* __restrict__ b_att,
    unsigned short* __restrict__ XP, int ns)
{
  __shared__ float tsh[HD];
  __shared__ float sm[512];
  __shared__ float red[8];
  const int node = ns + blockIdx.x;
  const int tid = threadIdx.x, wv = tid>>6, ln = tid&63;

  float s0p = 0.f;
  for (int c = tid; c < HD; c += 256) {
    tsh[c] = Tb[(size_t)node*HD + c];
    float h = Hb[(size_t)node*HD + c];
    s0p = fmaf(b_att[c], h, s0p);
    XP[(size_t)node*2048 + c] = f2bf(h);
  }
  #pragma unroll
  for (int o=32;o;o>>=1) s0p += __shfl_xor(s0p,o,64);
  if (ln==0) red[wv] = s0p;
  __syncthreads();
  float s0 = red[0]+red[1]+red[2]+red[3];

  const float4* tsh4 = (const float4*)tsh;
  for (int l = wv; l < 512; l += 4) {
    const float4* ar = (const float4*)(ann + (size_t)l*HD);
    float a = 0.f;
    #pragma unroll
    for (int q=0; q<4; ++q) {
      float4 wv4 = ar[q*64 + ln];
      float4 tv4 = tsh4[q*64 + ln];
      DOT4(a, wv4, tv4);
    }
    #pragma unroll
    for (int o=32;o;o>>=1) a += __shfl_xor(a,o,64);
    if (ln==0) sm[l] = a + s0;
  }
  __syncthreads();

  float m = -1e30f;
  for (int l=tid; l<512; l+=256) m = fmaxf(m, sm[l]);
  #pragma unroll
  for (int o=32;o;o>>=1) m = fmaxf(m, __shfl_xor(m,o,64));
  if (ln==0) red[wv]=m;
  __syncthreads();
  m = fmaxf(fmaxf(red[0],red[1]),fmaxf(red[2],red[3]));
  float se = 0.f;
  for (int l=tid; l<512; l+=256){ float ev=__expf(sm[l]-m); sm[l]=ev; se+=ev; }
  __syncthreads();
  #pragma unroll
  for (int o=32;o;o>>=1) se += __shfl_xor(se,o,64);
  if (ln==0) red[wv]=se;
  __syncthreads();
  float invS = 1.f/(red[0]+red[1]+red[2]+red[3]);

  float4 a4 = {0.f,0.f,0.f,0.f};
  const float4* ann4 = (const float4*)ann;
  for (int l = 0; l < 512; ++l) {
    float pl = sm[l];
    float4 av = ann4[(size_t)l*256 + tid];
    a4.x = fmaf(pl, av.x, a4.x); a4.y = fmaf(pl, av.y, a4.y);
    a4.z = fmaf(pl, av.z, a4.z); a4.w = fmaf(pl, av.w, a4.w);
  }
  unsigned short* xp = XP + (size_t)node*2048 + 1024 + tid*4;
  xp[0]=f2bf(a4.x*invS); xp[1]=f2bf(a4.y*invS); xp[2]=f2bf(a4.z*invS); xp[3]=f2bf(a4.w*invS);
}

// ---------------- loss per node ----------------
__global__ __launch_bounds__(256) void k_loss(const float* __restrict__ Lg,
                                              const int* __restrict__ values,
                                              float* __restrict__ Nl)
{
  __shared__ float red[8];
  const int node = blockIdx.x;
  const int tid = threadIdx.x, wv = tid>>6, ln = tid&63;
  const float* lg = Lg + (size_t)node*NCLS;

  float m = -1e30f;
  for (int i=tid;i<NCLS;i+=256) m = fmaxf(m, lg[i]);
  #pragma unroll
  for (int o=32;o;o>>=1) m = fmaxf(m, __shfl_xor(m,o,64));
  if (ln==0) red[wv]=m;
  __syncthreads();
  m = fmaxf(fmaxf(red[0],red[1]),fmaxf(red[2],red[3]));
  __syncthreads();

  float s = 0.f;
  for (int i=tid;i<NCLS;i+=256) s += __expf(lg[i]-m);
  #pragma unroll
  for (int o=32;o;o>>=1) s += __shfl_xor(s,o,64);
  if (ln==0) red[wv]=s;
  __syncthreads();
  s = red[0]+red[1]+red[2]+red[3];
  __syncthreads();
  float invs = 1.f/s;

  float q = 0.f;
  for (int i=tid;i<NCLS;i+=256) q += __expf(__expf(lg[i]-m)*invs);
  #pragma unroll
  for (int o=32;o;o>>=1) q += __shfl_xor(q,o,64);
  if (ln==0) red[wv]=q;
  __syncthreads();
  if (tid==0) {
    float qq = red[0]+red[1]+red[2]+red[3];
    int v = values[node];
    float pv = __expf(lg[v]-m)*invs;
    float nl = __logf(qq) - pv;
    if (v == NCLS-1) nl *= 0.2f;
    Nl[node] = nl;
  }
}

__global__ __launch_bounds__(256) void k_final(const float* __restrict__ Nl, float* __restrict__ out){
  __shared__ float red[8];
  int tid = threadIdx.x, wv = tid>>6, ln = tid&63;
  float s = Nl[tid];
  #pragma unroll
  for (int o=32;o;o>>=1) s += __shfl_xor(s,o,64);
  if (ln==0) red[wv]=s;
  __syncthreads();
  if (tid==0) out[0] = red[0]+red[1]+red[2]+red[3];
}

static inline void gemm(hipStream_t st, int MT, dim3 grid,
    const unsigned short* A, const float* B1, int K1, const float* B2, int K2,
    const float* bias, float* Cf, unsigned short* Cb16, int ostride, int N,
    int Mbase, int lstm, int aZ, int b1Z, int b2Z, int cZ, int tanhf)
{
  #define GCASE(MTv) k_gemm<MTv><<<grid, 256, 0, st>>>(A,B1,K1,B2,K2,bias,Cf,Cb16,ostride,N,Mbase,lstm,aZ,b1Z,b2Z,cZ,tanhf)
  switch(MT){
    case 1:  GCASE(1);  break;
    case 3:  GCASE(3);  break;
    case 4:  GCASE(4);  break;
    case 11: GCASE(11); break;
    default: GCASE(16); break;
  }
  #undef GCASE
}

// split-K gemm + reduce: OUT[row][col] = act(A[row]·B[col] + bias[col])
static inline void gemm_sk(hipStream_t st, int MT, const unsigned short* A,
    const float* B1, int K1, const float* B2, int K2, float* P,
    const float* bias, float* Cf, unsigned short* Cb16, int ostride,
    int N, int M, int tanhf)
{
  int K = K1 + K2;
  int KS = K / 128;
  dim3 grid(N/64, KS);
  #define SKCASE(MTv) k_gemm_sk<MTv><<<grid, 256, 0, st>>>(A,B1,K1,B2,K2,P,N,M)
  switch(MT){
    case 1:  SKCASE(1);  break;
    case 3:  SKCASE(3);  break;
    case 4:  SKCASE(4);  break;
    case 11: SKCASE(11); break;
    default: SKCASE(16); break;
  }
  #undef SKCASE
  int total = M*N;
  k_red<<<(total+255)/256, 256, 0, st>>>(P, KS, M, N, bias, tanhf, Cf, Cb16, ostride);
}

extern "C" void kernel_launch(void* const* d_in, const int* in_sizes, int n_in,
                              void* d_out, int out_size, void* d_ws, size_t ws_size,
                              hipStream_t stream)
{
  const float* rootH = (const float*)d_in[0];
  const float* rootC = (const float*)d_in[1];
  const float* ann   = (const float*)d_in[2];
  const int*   values= (const int*)d_in[3];
  const float* emb   = (const float*)d_in[6];
  const float* W_ih  = (const float*)d_in[7];
  const float* W_hh  = (const float*)d_in[8];
  const float* b_ih  = (const float*)d_in[9];
  const float* b_hh  = (const float*)d_in[10];
  const float* W_att = (const float*)d_in[11];
  const float* b_att = (const float*)d_in[12];
  const float* W_pre = (const float*)d_in[13];
  const float* b_pre = (const float*)d_in[14];
  const float* W_out = (const float*)d_in[15];
  const float* b_out = (const float*)d_in[16];

  float* ws = (float*)d_ws;
  float* WT = ws;  ws += 1024*1024;           // fp32 W_att^T
  float* Hb = ws;  ws += 256*1024;            // fp32 h
  float* Cb = ws;  ws += 256*1024;            // fp32 c
  float* Tb = ws;  ws += 256*1024;            // fp32 t = W_att^T h
  float* G  = ws;  ws += 4*48*4096;           // fp32 LSTM gates per slot
  float* Lg = ws;  ws += (size_t)256*NCLS;    // fp32 logits
  float* Nl = ws;  ws += 256;
  float* Psk= ws;  ws += 16*176*1024;         // split-K partials (max KS=16, M<=176)
  unsigned short* Hbf = (unsigned short*)ws;  // bf16 h            [256][1024]
  unsigned short* Etb = Hbf + 256*1024;       // bf16 et           [256][1024]
  unsigned short* XP  = Etb + 256*1024;       // bf16 [h|ctx]      [256][2048]
  unsigned short* Xb  = XP  + 256*2048;       // bf16 lstm input   [4][48][2560]

  k_tr  <<<dim3(32,32), 256, 0, stream>>>(W_att, WT);
  k_root<<<4,           256, 0, stream>>>(rootH, rootC, Hb, Cb, Hbf);

  const int LS[6] = {0,1,5,21,85,256};
  // level 0 (root)
  gemm_sk(stream, 1, Hbf, WT, 1024, nullptr,0, Psk, nullptr, Tb, nullptr, 1024, 1024, 1, 0);
  k_att2<<<1,256,0,stream>>>(ann, Tb, Hb, b_att, XP, 0);
  gemm_sk(stream, 1, XP, W_pre, 2048, nullptr,0, Psk, b_pre, nullptr, Etb, 1024, 1024, 1, 1);

  for (int lev=1; lev<5; ++lev){
    int s=LS[lev], e=LS[lev+1], n=e-s;
    k_xasm<<<n,256,0,stream>>>(emb, values, Etb, Hb, Xb, s, e);
    int mtl = (lev==4) ? 3 : 1;
    gemm(stream, mtl, dim3(64,1,4), Xb, W_ih, 1536, W_hh, 1024, nullptr, G, nullptr,
         4096, 4096, n, 1, 48*2560, 4096*1536, 4096*1024, 48*4096, 0);
    k_epi<<<n,256,0,stream>>>(G, b_ih, b_hh, Hb, Cb, Hbf, s, e);
    int mtn = (n+15)/16;
    gemm_sk(stream, mtn, Hbf + (size_t)s*1024, WT, 1024, nullptr,0, Psk, nullptr,
            Tb + (size_t)s*1024, nullptr, 1024, 1024, n, 0);
    k_att2<<<n,256,0,stream>>>(ann, Tb, Hb, b_att, XP, s);
    gemm_sk(stream, mtn, XP + (size_t)s*2048, W_pre, 2048, nullptr,0, Psk, b_pre, nullptr,
            Etb + (size_t)s*1024, 1024, 1024, n, 1);
  }

  gemm(stream, 16, dim3(157,1,1), Etb, W_out, 1024, nullptr,0, b_out, Lg, nullptr,
       10001, 10001, 256, 0, 0,0,0,0, 0);
  k_loss <<<256,256,0,stream>>>(Lg, values, Nl);
  k_final<<<1,  256,0,stream>>>(Nl, (float*)d_out);
}

// Round 5
// 571.102 us; speedup vs baseline: 2.7955x; 1.5899x over previous
//
#include <hip/hip_runtime.h>
#include <hip/hip_bf16.h>
#include <math.h>

#define HD 1024
#define NCLS 10001

typedef short s16x8 __attribute__((ext_vector_type(8)));
typedef float f32x4 __attribute__((ext_vector_type(4)));
#define MFMA16(a_, b_, c_) __builtin_amdgcn_mfma_f32_16x16x32_bf16((a_), (b_), (c_), 0, 0, 0)

__device__ __forceinline__ float sigf(float x){ return 1.f/(1.f+__expf(-x)); }
__device__ __forceinline__ float tanhfast(float x){
  x = fminf(fmaxf(x,-10.f),10.f);
  float e2 = __expf(2.f*x);
  return (e2-1.f)/(e2+1.f);
}
__device__ __forceinline__ unsigned short f2bf(float f){
  unsigned int u = __float_as_uint(f);
  u += 0x7FFF + ((u >> 16) & 1);          // round-to-nearest-even
  return (unsigned short)(u >> 16);
}

// ---------------- fp32 -> bf16 bulk convert ----------------
__global__ __launch_bounds__(256) void k_cvt(const float* __restrict__ A, unsigned short* __restrict__ B, int n){
  int i = (blockIdx.x*256 + threadIdx.x)*4;
  if (i < n){
    float4 v = *(const float4*)(A+i);
    B[i]=f2bf(v.x); B[i+1]=f2bf(v.y); B[i+2]=f2bf(v.z); B[i+3]=f2bf(v.w);
  }
}

// ---------------- generic transpose A[R][C] -> AT[C][R] (R,C mult of 32) ----------------
__global__ __launch_bounds__(256) void k_tr2(const float* __restrict__ A, float* __restrict__ AT, int R, int C){
  __shared__ float tile[32][33];
  int bx = blockIdx.x*32, by = blockIdx.y*32;   // bx: col, by: row
  int tx = threadIdx.x & 31, ty = threadIdx.x >> 5;
  #pragma unroll
  for (int yy = ty; yy < 32; yy += 8) tile[yy][tx] = A[(size_t)(by+yy)*C + bx+tx];
  __syncthreads();
  #pragma unroll
  for (int yy = ty; yy < 32; yy += 8) AT[(size_t)(bx+yy)*R + by+tx] = tile[tx][yy];
}

// ---------------- root state ----------------
__global__ __launch_bounds__(256) void k_root(const float* __restrict__ rH, const float* __restrict__ rC,
                                              float* __restrict__ Hb, float* __restrict__ Cb,
                                              unsigned short* __restrict__ Hbf, unsigned short* __restrict__ XP){
  int t = blockIdx.x*256 + threadIdx.x;
  if (t < HD){ Hb[t]=rH[t]; Cb[t]=rC[t]; Hbf[t]=f2bf(rH[t]); XP[t]=f2bf(rH[t]); }
}

// ---------------- X assembly for LSTM level ----------------
__global__ __launch_bounds__(256) void k_xasm(const float* __restrict__ emb, const int* __restrict__ values,
                                              const unsigned short* __restrict__ Etb, const float* __restrict__ Hb,
                                              unsigned short* __restrict__ X, int s, int e){
  int i = s + blockIdx.x;
  if (i >= e) return;
  int slot = (i - s) & 3, j = (i - s) >> 2;
  int p = (i - 1) >> 2;
  unsigned short* xr = X + ((size_t)slot*48 + j) * 2560;
  int tid = threadIdx.x;
  const float* er = emb + (size_t)values[p] * 512;
  for (int c = tid; c < 512;  c += 256) xr[c]        = f2bf(er[c]);
  const unsigned short* et = Etb + (size_t)p * 1024;
  for (int c = tid; c < 1024; c += 256) xr[512 + c]  = et[c];
  const float* hp = Hb + (size_t)p * 1024;
  for (int c = tid; c < 1024; c += 256) xr[1536 + c] = f2bf(hp[c]);
}

// ---------------- MFMA GEMM (full-K; LSTM / W_out / AHV). Row tile via blockIdx.y ----------------
template<int MT>
__global__ __launch_bounds__(256) void k_gemm(
    const unsigned short* __restrict__ A,
    const float* __restrict__ B1, int K1,
    const float* __restrict__ B2, int K2,
    const float* __restrict__ bias,
    float* __restrict__ Cf, unsigned short* __restrict__ Cb16,
    int ostride, int N, int Mbase, int lstm_mode,
    int aZ, int b1Z, int b2Z, int cZ, int tanh_flag)
{
  const int z = blockIdx.z;
  const int M = lstm_mode ? ((Mbase - z + 3) >> 2) : Mbase;
  const int mb0 = blockIdx.y * (MT*16);
  const unsigned short* Az = A + (size_t)z * aZ;
  const float* B1z = B1 + (size_t)z * b1Z;
  const float* B2z = B2 ? (B2 + (size_t)z * b2Z) : nullptr;
  const int K = K1 + K2;
  const int wv = threadIdx.x >> 6, lane = threadIdx.x & 63;
  const int col = (blockIdx.x*4 + wv)*16 + (lane & 15);
  const int colc = min(col, N-1);
  const int khalf = (lane >> 4) * 8;

  f32x4 acc[MT];
  #pragma unroll
  for (int m = 0; m < MT; ++m) acc[m] = (f32x4){0.f,0.f,0.f,0.f};
  int arow[MT];
  #pragma unroll
  for (int m = 0; m < MT; ++m) arow[m] = min(mb0 + m*16 + (lane & 15), M-1);

  for (int kk = 0; kk < K; kk += 32) {
    int kb = kk + khalf;
    const float* bp = (kb < K1) ? (B1z + (size_t)colc * K1 + kb)
                                : (B2z + (size_t)colc * K2 + (kb - K1));
    float4 b0 = *(const float4*)bp;
    float4 b1 = *(const float4*)(bp + 4);
    s16x8 bf;
    bf[0]=(short)f2bf(b0.x); bf[1]=(short)f2bf(b0.y); bf[2]=(short)f2bf(b0.z); bf[3]=(short)f2bf(b0.w);
    bf[4]=(short)f2bf(b1.x); bf[5]=(short)f2bf(b1.y); bf[6]=(short)f2bf(b1.z); bf[7]=(short)f2bf(b1.w);
    #pragma unroll
    for (int m = 0; m < MT; ++m) {
      s16x8 af = *(const s16x8*)(Az + (size_t)arow[m] * K + kb);
      acc[m] = MFMA16(af, bf, acc[m]);
    }
  }

  const int r0 = (lane >> 4) * 4;
  #pragma unroll
  for (int m = 0; m < MT; ++m) {
    #pragma unroll
    for (int q = 0; q < 4; ++q) {
      int row = mb0 + m*16 + r0 + q;
      if (row < M && col < N) {
        float v = acc[m][q] + (bias ? bias[col] : 0.f);
        if (tanh_flag) v = tanhfast(v);
        size_t off = (size_t)row * ostride + col + (size_t)z * cZ;
        if (Cb16) Cb16[off] = f2bf(v); else Cf[off] = v;
      }
    }
  }
}

// ---------------- split-K MFMA GEMM: partials P[ks][M][N] ----------------
template<int MT>
__global__ __launch_bounds__(256) void k_gemm_sk(
    const unsigned short* __restrict__ A,
    const float* __restrict__ B1, int K1,
    const float* __restrict__ B2, int K2,
    float* __restrict__ P, int N, int M)
{
  const int K = K1 + K2;
  const int ks = blockIdx.y;
  const int k0 = ks * 128;
  const int wv = threadIdx.x >> 6, lane = threadIdx.x & 63;
  const int col = (blockIdx.x*4 + wv)*16 + (lane & 15);
  const int colc = min(col, N-1);
  const int khalf = (lane >> 4) * 8;

  f32x4 acc[MT];
  #pragma unroll
  for (int m = 0; m < MT; ++m) acc[m] = (f32x4){0.f,0.f,0.f,0.f};
  int arow[MT];
  #pragma unroll
  for (int m = 0; m < MT; ++m) arow[m] = min(m*16 + (lane & 15), M-1);

  #pragma unroll
  for (int kk = 0; kk < 128; kk += 32) {
    int kb = k0 + kk + khalf;
    const float* bp = (kb < K1) ? (B1 + (size_t)colc * K1 + kb)
                                : (B2 + (size_t)colc * K2 + (kb - K1));
    float4 b0 = *(const float4*)bp;
    float4 b1 = *(const float4*)(bp + 4);
    s16x8 bf;
    bf[0]=(short)f2bf(b0.x); bf[1]=(short)f2bf(b0.y); bf[2]=(short)f2bf(b0.z); bf[3]=(short)f2bf(b0.w);
    bf[4]=(short)f2bf(b1.x); bf[5]=(short)f2bf(b1.y); bf[6]=(short)f2bf(b1.z); bf[7]=(short)f2bf(b1.w);
    #pragma unroll
    for (int m = 0; m < MT; ++m) {
      s16x8 af = *(const s16x8*)(A + (size_t)arow[m] * K + kb);
      acc[m] = MFMA16(af, bf, acc[m]);
    }
  }

  const int r0 = (lane >> 4) * 4;
  #pragma unroll
  for (int m = 0; m < MT; ++m) {
    #pragma unroll
    for (int q = 0; q < 4; ++q) {
      int row = m*16 + r0 + q;
      if (row < M && col < N)
        P[((size_t)ks*M + row)*N + col] = acc[m][q];
    }
  }
}

// ---------------- split-K reduction ----------------
__global__ __launch_bounds__(256) void k_red(const float* __restrict__ P, int KS, int M, int N,
                                             const float* __restrict__ bias, int tanh_flag,
                                             float* __restrict__ Cf, unsigned short* __restrict__ Cb16,
                                             int ostride)
{
  int idx = blockIdx.x*256 + threadIdx.x;
  if (idx >= M*N) return;
  int row = idx / N, col = idx - row*N;
  float s = bias ? bias[col] : 0.f;
  for (int ks = 0; ks < KS; ++ks) s += P[((size_t)ks*M + row)*N + col];
  if (tanh_flag) s = tanhfast(s);
  if (Cb16) Cb16[(size_t)row*ostride + col] = f2bf(s);
  else      Cf  [(size_t)row*ostride + col] = s;
}

// ---------------- fused split-K sum + softmax over 512 logits -> bf16 probs ----------------
__global__ __launch_bounds__(256) void k_soft(const float* __restrict__ P, int KS, int M,
                                              unsigned short* __restrict__ Pb)
{
  __shared__ float sm[512];
  __shared__ float red[8];
  const int m = blockIdx.x;
  const int tid = threadIdx.x, wv = tid>>6, ln = tid&63;
  for (int l = tid; l < 512; l += 256) {
    float s = 0.f;
    for (int ks = 0; ks < KS; ++ks) s += P[((size_t)ks*M + m)*512 + l];
    sm[l] = s;
  }
  __syncthreads();
  float mx = -1e30f;
  for (int l=tid; l<512; l+=256) mx = fmaxf(mx, sm[l]);
  #pragma unroll
  for (int o=32;o;o>>=1) mx = fmaxf(mx, __shfl_xor(mx,o,64));
  if (ln==0) red[wv]=mx;
  __syncthreads();
  mx = fmaxf(fmaxf(red[0],red[1]),fmaxf(red[2],red[3]));
  float se = 0.f;
  for (int l=tid; l<512; l+=256){ float ev=__expf(sm[l]-mx); sm[l]=ev; se+=ev; }
  __syncthreads();
  #pragma unroll
  for (int o=32;o;o>>=1) se += __shfl_xor(se,o,64);
  if (ln==0) red[wv]=se;
  __syncthreads();
  float invS = 1.f/(red[0]+red[1]+red[2]+red[3]);
  for (int l=tid; l<512; l+=256) Pb[(size_t)m*512 + l] = f2bf(sm[l]*invS);
}

// ---------------- LSTM epilogue ----------------
__global__ __launch_bounds__(256) void k_epi(const float* __restrict__ G,
                                             const float* __restrict__ b_ih, const float* __restrict__ b_hh,
                                             float* __restrict__ Hb, float* __restrict__ Cb,
                                             unsigned short* __restrict__ Hbf, unsigned short* __restrict__ XP,
                                             int s, int e){
  int i = s + blockIdx.x;
  if (i >= e) return;
  int slot = (i - s) & 3, j = (i - s) >> 2;
  int p = (i - 1) >> 2;
  const float* g  = G + ((size_t)slot*48 + j) * 4096;
  const float* bi = b_ih + (size_t)slot*4096;
  const float* bh = b_hh + (size_t)slot*4096;
  for (int u = threadIdx.x; u < 1024; u += 256) {
    float ig = g[u]      + bi[u]      + bh[u];
    float fg = g[1024+u] + bi[1024+u] + bh[1024+u];
    float gg = g[2048+u] + bi[2048+u] + bh[2048+u];
    float og = g[3072+u] + bi[3072+u] + bh[3072+u];
    float cp = Cb[(size_t)p*1024 + u];
    float c  = sigf(fg)*cp + sigf(ig)*tanhfast(gg);
    float h  = sigf(og)*tanhfast(c);
    Hb [(size_t)i*1024+u] = h;
    Cb [(size_t)i*1024+u] = c;
    Hbf[(size_t)i*1024+u] = f2bf(h);
    XP [(size_t)i*2048+u] = f2bf(h);
  }
}

// ---------------- loss per node ----------------
__global__ __launch_bounds__(256) void k_loss(const float* __restrict__ Lg,
                                              const int* __restrict__ values,
                                              float* __restrict__ Nl)
{
  __shared__ float red[8];
  const int node = blockIdx.x;
  const int tid = threadIdx.x, wv = tid>>6, ln = tid&63;
  const float* lg = Lg + (size_t)node*NCLS;

  float m = -1e30f;
  for (int i=tid;i<NCLS;i+=256) m = fmaxf(m, lg[i]);
  #pragma unroll
  for (int o=32;o;o>>=1) m = fmaxf(m, __shfl_xor(m,o,64));
  if (ln==0) red[wv]=m;
  __syncthreads();
  m = fmaxf(fmaxf(red[0],red[1]),fmaxf(red[2],red[3]));
  __syncthreads();

  float s = 0.f;
  for (int i=tid;i<NCLS;i+=256) s += __expf(lg[i]-m);
  #pragma unroll
  for (int o=32;o;o>>=1) s += __shfl_xor(s,o,64);
  if (ln==0) red[wv]=s;
  __syncthreads();
  s = red[0]+red[1]+red[2]+red[3];
  __syncthreads();
  float invs = 1.f/s;

  float q = 0.f;
  for (int i=tid;i<NCLS;i+=256) q += __expf(__expf(lg[i]-m)*invs);
  #pragma unroll
  for (int o=32;o;o>>=1) q += __shfl_xor(q,o,64);
  if (ln==0) red[wv]=q;
  __syncthreads();
  if (tid==0) {
    float qq = red[0]+red[1]+red[2]+red[3];
    int v = values[node];
    float pv = __expf(lg[v]-m)*invs;
    float nl = __logf(qq) - pv;
    if (v == NCLS-1) nl *= 0.2f;
    Nl[node] = nl;
  }
}

__global__ __launch_bounds__(256) void k_final(const float* __restrict__ Nl, float* __restrict__ out){
  __shared__ float red[8];
  int tid = threadIdx.x, wv = tid>>6, ln = tid&63;
  float s = Nl[tid];
  #pragma unroll
  for (int o=32;o;o>>=1) s += __shfl_xor(s,o,64);
  if (ln==0) red[wv]=s;
  __syncthreads();
  if (tid==0) out[0] = red[0]+red[1]+red[2]+red[3];
}

static inline void gemm(hipStream_t st, int MT, dim3 grid,
    const unsigned short* A, const float* B1, int K1, const float* B2, int K2,
    const float* bias, float* Cf, unsigned short* Cb16, int ostride, int N,
    int Mbase, int lstm, int aZ, int b1Z, int b2Z, int cZ, int tanhf)
{
  #define GCASE(MTv) k_gemm<MTv><<<grid, 256, 0, st>>>(A,B1,K1,B2,K2,bias,Cf,Cb16,ostride,N,Mbase,lstm,aZ,b1Z,b2Z,cZ,tanhf)
  switch(MT){
    case 1:  GCASE(1);  break;
    case 3:  GCASE(3);  break;
    case 4:  GCASE(4);  break;
    case 11: GCASE(11); break;
    default: GCASE(16); break;
  }
  #undef GCASE
}

// split-K partials only (no reduce)
static inline void gemm_sk_part(hipStream_t st, int MT, const unsigned short* A,
    const float* B1, int K1, const float* B2, int K2, float* P, int N, int M)
{
  int K = K1 + K2;
  int KS = K / 128;
  dim3 grid(N/64, KS);
  #define SKCASE(MTv) k_gemm_sk<MTv><<<grid, 256, 0, st>>>(A,B1,K1,B2,K2,P,N,M)
  switch(MT){
    case 1:  SKCASE(1);  break;
    case 3:  SKCASE(3);  break;
    case 4:  SKCASE(4);  break;
    case 11: SKCASE(11); break;
    default: SKCASE(16); break;
  }
  #undef SKCASE
}

static inline void gemm_sk(hipStream_t st, int MT, const unsigned short* A,
    const float* B1, int K1, const float* B2, int K2, float* P,
    const float* bias, float* Cf, unsigned short* Cb16, int ostride,
    int N, int M, int tanhf)
{
  gemm_sk_part(st, MT, A, B1, K1, B2, K2, P, N, M);
  int KS = (K1+K2)/128;
  int total = M*N;
  k_red<<<(total+255)/256, 256, 0, st>>>(P, KS, M, N, bias, tanhf, Cf, Cb16, ostride);
}

extern "C" void kernel_launch(void* const* d_in, const int* in_sizes, int n_in,
                              void* d_out, int out_size, void* d_ws, size_t ws_size,
                              hipStream_t stream)
{
  const float* rootH = (const float*)d_in[0];
  const float* rootC = (const float*)d_in[1];
  const float* ann   = (const float*)d_in[2];
  const int*   values= (const int*)d_in[3];
  const float* emb   = (const float*)d_in[6];
  const float* W_ih  = (const float*)d_in[7];
  const float* W_hh  = (const float*)d_in[8];
  const float* b_ih  = (const float*)d_in[9];
  const float* b_hh  = (const float*)d_in[10];
  const float* W_att = (const float*)d_in[11];
  const float* b_att = (const float*)d_in[12];
  const float* W_pre = (const float*)d_in[13];
  const float* b_pre = (const float*)d_in[14];
  const float* W_out = (const float*)d_in[15];
  const float* b_out = (const float*)d_in[16];

  float* ws = (float*)d_ws;
  float* Hb  = ws; ws += 256*1024;            // fp32 h
  float* Cb  = ws; ws += 256*1024;            // fp32 c
  float* G   = ws; ws += 4*48*4096;           // fp32 LSTM gates per slot
  float* AHV = ws; ws += 512*1024;            // fp32 ann@W_att^T + b_att
  float* AnT = ws; ws += 1024*512;            // fp32 ann^T
  float* Lg  = ws; ws += (size_t)256*NCLS;    // fp32 logits
  float* Nl  = ws; ws += 256;
  float* Psk = ws; ws += 16*176*1024;         // split-K partials
  unsigned short* Hbf = (unsigned short*)ws;  // bf16 h            [256][1024]
  unsigned short* Etb = Hbf + 256*1024;       // bf16 et           [256][1024]
  unsigned short* XP  = Etb + 256*1024;       // bf16 [h|ctx]      [256][2048]
  unsigned short* Xb  = XP  + 256*2048;       // bf16 lstm input   [4][48][2560]
  unsigned short* Annb= Xb  + 4*48*2560;      // bf16 ann          [512][1024]
  unsigned short* Pb  = Annb+ 512*1024;       // bf16 probs        [<=176][512]

  // one-time preprocessing
  k_cvt<<<512, 256, 0, stream>>>(ann, Annb, 512*1024);
  k_tr2<<<dim3(32,16), 256, 0, stream>>>(ann, AnT, 512, 1024);
  gemm(stream, 4, dim3(16,8,1), Annb, W_att, 1024, nullptr,0, b_att, AHV, nullptr,
       1024, 1024, 512, 0, 0,0,0,0, 0);
  k_root<<<4, 256, 0, stream>>>(rootH, rootC, Hb, Cb, Hbf, XP);

  const int LS[6] = {0,1,5,21,85,256};
  for (int lev=0; lev<5; ++lev){
    int s=LS[lev], e=LS[lev+1], n=e-s;
    if (lev>0){
      k_xasm<<<n,256,0,stream>>>(emb, values, Etb, Hb, Xb, s, e);
      int mtl = (lev==4) ? 3 : 1;
      gemm(stream, mtl, dim3(64,1,4), Xb, W_ih, 1536, W_hh, 1024, nullptr, G, nullptr,
           4096, 4096, n, 1, 48*2560, 4096*1536, 4096*1024, 48*4096, 0);
      k_epi<<<n,256,0,stream>>>(G, b_ih, b_hh, Hb, Cb, Hbf, XP, s, e);
    }
    int mtn = (n+15)/16;
    // attention logits: [n x 512] = h · AHV^T  (split-K, fused softmax)
    gemm_sk_part(stream, mtn, Hbf + (size_t)s*1024, AHV, 1024, nullptr,0, Psk, 512, n);
    k_soft<<<n,256,0,stream>>>(Psk, 8, n, Pb);
    // ctx: [n x 1024] = probs · ann  (split-K + reduce -> XP ctx half)
    gemm_sk(stream, mtn, Pb, AnT, 512, nullptr,0, Psk, nullptr, nullptr,
            XP + (size_t)s*2048 + 1024, 2048, 1024, n, 0);
    // et = tanh(W_pre [h|ctx] + b_pre)
    gemm_sk(stream, mtn, XP + (size_t)s*2048, W_pre, 2048, nullptr,0, Psk, b_pre, nullptr,
            Etb + (size_t)s*1024, 1024, 1024, n, 1);
  }

  gemm(stream, 4, dim3(157,4,1), Etb, W_out, 1024, nullptr,0, b_out, Lg, nullptr,
       10001, 10001, 256, 0, 0,0,0,0, 0);
  k_loss <<<256,256,0,stream>>>(Lg, values, Nl);
  k_final<<<1,  256,0,stream>>>(Nl, (float*)d_out);
}

// Round 6
// 530.368 us; speedup vs baseline: 3.0102x; 1.0768x over previous
//
#include <hip/hip_runtime.h>
#include <hip/hip_bf16.h>
#include <math.h>

#define HD 1024
#define NCLS 10001

typedef short s16x8 __attribute__((ext_vector_type(8)));
typedef float f32x4 __attribute__((ext_vector_type(4)));
#define MFMA16(a_, b_, c_) __builtin_amdgcn_mfma_f32_16x16x32_bf16((a_), (b_), (c_), 0, 0, 0)

__device__ __forceinline__ float sigf(float x){ return 1.f/(1.f+__expf(-x)); }
__device__ __forceinline__ float tanhfast(float x){
  x = fminf(fmaxf(x,-10.f),10.f);
  float e2 = __expf(2.f*x);
  return (e2-1.f)/(e2+1.f);
}
__device__ __forceinline__ unsigned short f2bf(float f){
  unsigned int u = __float_as_uint(f);
  u += 0x7FFF + ((u >> 16) & 1);          // round-to-nearest-even
  return (unsigned short)(u >> 16);
}

// ---------------- fp32 -> bf16 bulk convert ----------------
__global__ __launch_bounds__(256) void k_cvt(const float* __restrict__ A, unsigned short* __restrict__ B, int n){
  int i = (blockIdx.x*256 + threadIdx.x)*4;
  if (i < n){
    float4 v = *(const float4*)(A+i);
    B[i]=f2bf(v.x); B[i+1]=f2bf(v.y); B[i+2]=f2bf(v.z); B[i+3]=f2bf(v.w);
  }
}

// ---------------- generic transpose A[R][C] -> AT[C][R] (R,C mult of 32) ----------------
__global__ __launch_bounds__(256) void k_tr2(const float* __restrict__ A, float* __restrict__ AT, int R, int C){
  __shared__ float tile[32][33];
  int bx = blockIdx.x*32, by = blockIdx.y*32;
  int tx = threadIdx.x & 31, ty = threadIdx.x >> 5;
  #pragma unroll
  for (int yy = ty; yy < 32; yy += 8) tile[yy][tx] = A[(size_t)(by+yy)*C + bx+tx];
  __syncthreads();
  #pragma unroll
  for (int yy = ty; yy < 32; yy += 8) AT[(size_t)(bx+yy)*R + by+tx] = tile[tx][yy];
}

// ---------------- root state ----------------
__global__ __launch_bounds__(256) void k_root(const float* __restrict__ rH, const float* __restrict__ rC,
                                              float* __restrict__ Hb, float* __restrict__ Cb,
                                              unsigned short* __restrict__ Hbf, unsigned short* __restrict__ XP){
  int t = blockIdx.x*256 + threadIdx.x;
  if (t < HD){ Hb[t]=rH[t]; Cb[t]=rC[t]; Hbf[t]=f2bf(rH[t]); XP[t]=f2bf(rH[t]); }
}

// ---------------- X assembly for LSTM level ----------------
__global__ __launch_bounds__(256) void k_xasm(const float* __restrict__ emb, const int* __restrict__ values,
                                              const unsigned short* __restrict__ Etb, const float* __restrict__ Hb,
                                              unsigned short* __restrict__ X, int s, int e){
  int i = s + blockIdx.x;
  if (i >= e) return;
  int slot = (i - s) & 3, j = (i - s) >> 2;
  int p = (i - 1) >> 2;
  unsigned short* xr = X + ((size_t)slot*48 + j) * 2560;
  int tid = threadIdx.x;
  const float* er = emb + (size_t)values[p] * 512;
  for (int c = tid; c < 512;  c += 256) xr[c]        = f2bf(er[c]);
  const unsigned short* et = Etb + (size_t)p * 1024;
  for (int c = tid; c < 1024; c += 256) xr[512 + c]  = et[c];
  const float* hp = Hb + (size_t)p * 1024;
  for (int c = tid; c < 1024; c += 256) xr[1536 + c] = f2bf(hp[c]);
}

// ---------------- MFMA GEMM (full-K; AHV). Row tile via blockIdx.y ----------------
template<int MT>
__global__ __launch_bounds__(256) void k_gemm(
    const unsigned short* __restrict__ A,
    const float* __restrict__ B1, int K1,
    const float* __restrict__ bias,
    float* __restrict__ Cf,
    int ostride, int N, int M)
{
  const int mb0 = blockIdx.y * (MT*16);
  const int K = K1;
  const int wv = threadIdx.x >> 6, lane = threadIdx.x & 63;
  const int col = (blockIdx.x*4 + wv)*16 + (lane & 15);
  const int colc = min(col, N-1);
  const int khalf = (lane >> 4) * 8;

  f32x4 acc[MT];
  #pragma unroll
  for (int m = 0; m < MT; ++m) acc[m] = (f32x4){0.f,0.f,0.f,0.f};
  int arow[MT];
  #pragma unroll
  for (int m = 0; m < MT; ++m) arow[m] = min(mb0 + m*16 + (lane & 15), M-1);

  #pragma unroll 4
  for (int kk = 0; kk < K; kk += 32) {
    int kb = kk + khalf;
    const float* bp = B1 + (size_t)colc * K1 + kb;
    float4 b0 = *(const float4*)bp;
    float4 b1 = *(const float4*)(bp + 4);
    s16x8 bf;
    bf[0]=(short)f2bf(b0.x); bf[1]=(short)f2bf(b0.y); bf[2]=(short)f2bf(b0.z); bf[3]=(short)f2bf(b0.w);
    bf[4]=(short)f2bf(b1.x); bf[5]=(short)f2bf(b1.y); bf[6]=(short)f2bf(b1.z); bf[7]=(short)f2bf(b1.w);
    #pragma unroll
    for (int m = 0; m < MT; ++m) {
      s16x8 af = *(const s16x8*)(A + (size_t)arow[m] * K + kb);
      acc[m] = MFMA16(af, bf, acc[m]);
    }
  }

  const int r0 = (lane >> 4) * 4;
  #pragma unroll
  for (int m = 0; m < MT; ++m) {
    #pragma unroll
    for (int q = 0; q < 4; ++q) {
      int row = mb0 + m*16 + r0 + q;
      if (row < M && col < N)
        Cf[(size_t)row * ostride + col] = acc[m][q] + (bias ? bias[col] : 0.f);
    }
  }
}

// ---------------- split-K + z-batched MFMA GEMM: partials P[(z*KS+ks)*Mpad + row][N] ----------------
// grid (N/64, KS, NZ). chunk = KITER*32 along K.
template<int MT, int KITER>
__global__ __launch_bounds__(256) void k_gemm_skz(
    const unsigned short* __restrict__ A,
    const float* __restrict__ B1, int K1,
    const float* __restrict__ B2, int K2,
    float* __restrict__ P, int N, int Mbase, int lstm_mode, int Mpad,
    int aZ, int b1Z, int b2Z, int KS)
{
  const int z = blockIdx.z;
  const int M = lstm_mode ? ((Mbase - z + 3) >> 2) : Mbase;
  const unsigned short* Az = A + (size_t)z * aZ;
  const float* B1z = B1 + (size_t)z * b1Z;
  const float* B2z = B2 ? (B2 + (size_t)z * b2Z) : nullptr;
  const int K = K1 + K2;
  const int ks = blockIdx.y;
  const int k0 = ks * (KITER*32);
  const int wv = threadIdx.x >> 6, lane = threadIdx.x & 63;
  const int col = (blockIdx.x*4 + wv)*16 + (lane & 15);
  const int colc = min(col, N-1);
  const int khalf = (lane >> 4) * 8;

  f32x4 acc[MT];
  #pragma unroll
  for (int m = 0; m < MT; ++m) acc[m] = (f32x4){0.f,0.f,0.f,0.f};
  int arow[MT];
  #pragma unroll
  for (int m = 0; m < MT; ++m) arow[m] = min(m*16 + (lane & 15), M-1);

  #pragma unroll 4
  for (int kk = 0; kk < KITER*32; kk += 32) {
    int kb = k0 + kk + khalf;
    const float* bp = (kb < K1) ? (B1z + (size_t)colc * K1 + kb)
                                : (B2z + (size_t)colc * K2 + (kb - K1));
    float4 b0 = *(const float4*)bp;
    float4 b1 = *(const float4*)(bp + 4);
    s16x8 bf;
    bf[0]=(short)f2bf(b0.x); bf[1]=(short)f2bf(b0.y); bf[2]=(short)f2bf(b0.z); bf[3]=(short)f2bf(b0.w);
    bf[4]=(short)f2bf(b1.x); bf[5]=(short)f2bf(b1.y); bf[6]=(short)f2bf(b1.z); bf[7]=(short)f2bf(b1.w);
    #pragma unroll
    for (int m = 0; m < MT; ++m) {
      s16x8 af = *(const s16x8*)(Az + (size_t)arow[m] * K + kb);
      acc[m] = MFMA16(af, bf, acc[m]);
    }
  }

  const int r0 = (lane >> 4) * 4;
  #pragma unroll
  for (int m = 0; m < MT; ++m) {
    #pragma unroll
    for (int q = 0; q < 4; ++q) {
      int row = m*16 + r0 + q;
      if (row < M && col < N)
        P[(((size_t)z*KS + ks)*Mpad + row)*N + col] = acc[m][q];
    }
  }
}

// ---------------- split-K MFMA GEMM (small path): partials P[ks][M][N] ----------------
template<int MT>
__global__ __launch_bounds__(256) void k_gemm_sk(
    const unsigned short* __restrict__ A,
    const float* __restrict__ B1, int K1,
    const float* __restrict__ B2, int K2,
    float* __restrict__ P, int N, int M)
{
  const int K = K1 + K2;
  const int ks = blockIdx.y;
  const int k0 = ks * 128;
  const int wv = threadIdx.x >> 6, lane = threadIdx.x & 63;
  const int col = (blockIdx.x*4 + wv)*16 + (lane & 15);
  const int colc = min(col, N-1);
  const int khalf = (lane >> 4) * 8;

  f32x4 acc[MT];
  #pragma unroll
  for (int m = 0; m < MT; ++m) acc[m] = (f32x4){0.f,0.f,0.f,0.f};
  int arow[MT];
  #pragma unroll
  for (int m = 0; m < MT; ++m) arow[m] = min(m*16 + (lane & 15), M-1);

  #pragma unroll
  for (int kk = 0; kk < 128; kk += 32) {
    int kb = k0 + kk + khalf;
    const float* bp = (kb < K1) ? (B1 + (size_t)colc * K1 + kb)
                                : (B2 + (size_t)colc * K2 + (kb - K1));
    float4 b0 = *(const float4*)bp;
    float4 b1 = *(const float4*)(bp + 4);
    s16x8 bf;
    bf[0]=(short)f2bf(b0.x); bf[1]=(short)f2bf(b0.y); bf[2]=(short)f2bf(b0.z); bf[3]=(short)f2bf(b0.w);
    bf[4]=(short)f2bf(b1.x); bf[5]=(short)f2bf(b1.y); bf[6]=(short)f2bf(b1.z); bf[7]=(short)f2bf(b1.w);
    #pragma unroll
    for (int m = 0; m < MT; ++m) {
      s16x8 af = *(const s16x8*)(A + (size_t)arow[m] * K + kb);
      acc[m] = MFMA16(af, bf, acc[m]);
    }
  }

  const int r0 = (lane >> 4) * 4;
  #pragma unroll
  for (int m = 0; m < MT; ++m) {
    #pragma unroll
    for (int q = 0; q < 4; ++q) {
      int row = m*16 + r0 + q;
      if (row < M && col < N)
        P[((size_t)ks*M + row)*N + col] = acc[m][q];
    }
  }
}

// ---------------- split-K reduction ----------------
__global__ __launch_bounds__(256) void k_red(const float* __restrict__ P, int KS, int M, int N,
                                             const float* __restrict__ bias, int tanh_flag,
                                             float* __restrict__ Cf, unsigned short* __restrict__ Cb16,
                                             int ostride)
{
  int idx = blockIdx.x*256 + threadIdx.x;
  if (idx >= M*N) return;
  int row = idx / N, col = idx - row*N;
  float s = bias ? bias[col] : 0.f;
  for (int ks = 0; ks < KS; ++ks) s += P[((size_t)ks*M + row)*N + col];
  if (tanh_flag) s = tanhfast(s);
  if (Cb16) Cb16[(size_t)row*ostride + col] = f2bf(s);
  else      Cf  [(size_t)row*ostride + col] = s;
}

// ---------------- fused split-K sum + softmax over 512 logits -> bf16 probs ----------------
__global__ __launch_bounds__(256) void k_soft(const float* __restrict__ P, int KS, int M,
                                              unsigned short* __restrict__ Pb)
{
  __shared__ float sm[512];
  __shared__ float red[8];
  const int m = blockIdx.x;
  const int tid = threadIdx.x, wv = tid>>6, ln = tid&63;
  for (int l = tid; l < 512; l += 256) {
    float s = 0.f;
    for (int ks = 0; ks < KS; ++ks) s += P[((size_t)ks*M + m)*512 + l];
    sm[l] = s;
  }
  __syncthreads();
  float mx = -1e30f;
  for (int l=tid; l<512; l+=256) mx = fmaxf(mx, sm[l]);
  #pragma unroll
  for (int o=32;o;o>>=1) mx = fmaxf(mx, __shfl_xor(mx,o,64));
  if (ln==0) red[wv]=mx;
  __syncthreads();
  mx = fmaxf(fmaxf(red[0],red[1]),fmaxf(red[2],red[3]));
  float se = 0.f;
  for (int l=tid; l<512; l+=256){ float ev=__expf(sm[l]-mx); sm[l]=ev; se+=ev; }
  __syncthreads();
  #pragma unroll
  for (int o=32;o;o>>=1) se += __shfl_xor(se,o,64);
  if (ln==0) red[wv]=se;
  __syncthreads();
  float invS = 1.f/(red[0]+red[1]+red[2]+red[3]);
  for (int l=tid; l<512; l+=256) Pb[(size_t)m*512 + l] = f2bf(sm[l]*invS);
}

// ---------------- LSTM epilogue (sums KS=5 gate partials + biases) ----------------
__global__ __launch_bounds__(256) void k_epi(const float* __restrict__ P,
                                             const float* __restrict__ b_ih, const float* __restrict__ b_hh,
                                             float* __restrict__ Hb, float* __restrict__ Cb,
                                             unsigned short* __restrict__ Hbf, unsigned short* __restrict__ XP,
                                             int s, int e){
  int i = s + blockIdx.x;
  if (i >= e) return;
  int slot = (i - s) & 3, j = (i - s) >> 2;
  int p = (i - 1) >> 2;
  const float* bi = b_ih + (size_t)slot*4096;
  const float* bh = b_hh + (size_t)slot*4096;
  for (int u = threadIdx.x; u < 1024; u += 256) {
    float ig = bi[u]      + bh[u];
    float fg = bi[1024+u] + bh[1024+u];
    float gg = bi[2048+u] + bh[2048+u];
    float og = bi[3072+u] + bh[3072+u];
    #pragma unroll
    for (int ks = 0; ks < 5; ++ks) {
      const float* g = P + (((size_t)slot*5 + ks)*48 + j)*4096;
      ig += g[u]; fg += g[1024+u]; gg += g[2048+u]; og += g[3072+u];
    }
    float cp = Cb[(size_t)p*1024 + u];
    float c  = sigf(fg)*cp + sigf(ig)*tanhfast(gg);
    float h  = sigf(og)*tanhfast(c);
    Hb [(size_t)i*1024+u] = h;
    Cb [(size_t)i*1024+u] = c;
    Hbf[(size_t)i*1024+u] = f2bf(h);
    XP [(size_t)i*2048+u] = f2bf(h);
  }
}

// ---------------- loss per node ----------------
__global__ __launch_bounds__(256) void k_loss(const float* __restrict__ Lg,
                                              const int* __restrict__ values,
                                              float* __restrict__ Nl)
{
  __shared__ float red[8];
  const int node = blockIdx.x;
  const int tid = threadIdx.x, wv = tid>>6, ln = tid&63;
  const float* lg = Lg + (size_t)node*NCLS;

  float m = -1e30f;
  for (int i=tid;i<NCLS;i+=256) m = fmaxf(m, lg[i]);
  #pragma unroll
  for (int o=32;o;o>>=1) m = fmaxf(m, __shfl_xor(m,o,64));
  if (ln==0) red[wv]=m;
  __syncthreads();
  m = fmaxf(fmaxf(red[0],red[1]),fmaxf(red[2],red[3]));
  __syncthreads();

  float s = 0.f;
  for (int i=tid;i<NCLS;i+=256) s += __expf(lg[i]-m);
  #pragma unroll
  for (int o=32;o;o>>=1) s += __shfl_xor(s,o,64);
  if (ln==0) red[wv]=s;
  __syncthreads();
  s = red[0]+red[1]+red[2]+red[3];
  __syncthreads();
  float invs = 1.f/s;

  float q = 0.f;
  for (int i=tid;i<NCLS;i+=256) q += __expf(__expf(lg[i]-m)*invs);
  #pragma unroll
  for (int o=32;o;o>>=1) q += __shfl_xor(q,o,64);
  if (ln==0) red[wv]=q;
  __syncthreads();
  if (tid==0) {
    float qq = red[0]+red[1]+red[2]+red[3];
    int v = values[node];
    float pv = __expf(lg[v]-m)*invs;
    float nl = __logf(qq) - pv;
    if (v == NCLS-1) nl *= 0.2f;
    Nl[node] = nl;
  }
}

__global__ __launch_bounds__(256) void k_final(const float* __restrict__ Nl, float* __restrict__ out){
  __shared__ float red[8];
  int tid = threadIdx.x, wv = tid>>6, ln = tid&63;
  float s = Nl[tid];
  #pragma unroll
  for (int o=32;o;o>>=1) s += __shfl_xor(s,o,64);
  if (ln==0) red[wv]=s;
  __syncthreads();
  if (tid==0) out[0] = red[0]+red[1]+red[2]+red[3];
}

// split-K partials only (no reduce)
static inline void gemm_sk_part(hipStream_t st, int MT, const unsigned short* A,
    const float* B1, int K1, const float* B2, int K2, float* P, int N, int M)
{
  int K = K1 + K2;
  int KS = K / 128;
  dim3 grid(N/64, KS);
  #define SKCASE(MTv) k_gemm_sk<MTv><<<grid, 256, 0, st>>>(A,B1,K1,B2,K2,P,N,M)
  switch(MT){
    case 1:  SKCASE(1);  break;
    case 3:  SKCASE(3);  break;
    case 4:  SKCASE(4);  break;
    case 11: SKCASE(11); break;
    default: SKCASE(16); break;
  }
  #undef SKCASE
}

static inline void gemm_sk(hipStream_t st, int MT, const unsigned short* A,
    const float* B1, int K1, const float* B2, int K2, float* P,
    const float* bias, float* Cf, unsigned short* Cb16, int ostride,
    int N, int M, int tanhf)
{
  gemm_sk_part(st, MT, A, B1, K1, B2, K2, P, N, M);
  int KS = (K1+K2)/128;
  int total = M*N;
  k_red<<<(total+255)/256, 256, 0, st>>>(P, KS, M, N, bias, tanhf, Cf, Cb16, ostride);
}

extern "C" void kernel_launch(void* const* d_in, const int* in_sizes, int n_in,
                              void* d_out, int out_size, void* d_ws, size_t ws_size,
                              hipStream_t stream)
{
  const float* rootH = (const float*)d_in[0];
  const float* rootC = (const float*)d_in[1];
  const float* ann   = (const float*)d_in[2];
  const int*   values= (const int*)d_in[3];
  const float* emb   = (const float*)d_in[6];
  const float* W_ih  = (const float*)d_in[7];
  const float* W_hh  = (const float*)d_in[8];
  const float* b_ih  = (const float*)d_in[9];
  const float* b_hh  = (const float*)d_in[10];
  const float* W_att = (const float*)d_in[11];
  const float* b_att = (const float*)d_in[12];
  const float* W_pre = (const float*)d_in[13];
  const float* b_pre = (const float*)d_in[14];
  const float* W_out = (const float*)d_in[15];
  const float* b_out = (const float*)d_in[16];

  float* ws = (float*)d_ws;
  float* Hb  = ws; ws += 256*1024;            // fp32 h
  float* Cb  = ws; ws += 256*1024;            // fp32 c
  float* AHV = ws; ws += 512*1024;            // fp32 ann@W_att^T + b_att
  float* AnT = ws; ws += 1024*512;            // fp32 ann^T
  float* Lg  = ws; ws += (size_t)256*NCLS;    // fp32 logits
  float* Nl  = ws; ws += 256;
  float* PB  = ws; ws += (size_t)4*256*10001; // big partials: LSTM [4][5][48][4096] / W_out [4][256][10001]
  float* Psk = ws; ws += 16*176*1024;         // small split-K partials
  unsigned short* Hbf = (unsigned short*)ws;  // bf16 h            [256][1024]
  unsigned short* Etb = Hbf + 256*1024;       // bf16 et           [256][1024]
  unsigned short* XP  = Etb + 256*1024;       // bf16 [h|ctx]      [256][2048]
  unsigned short* Xb  = XP  + 256*2048;       // bf16 lstm input   [4][48][2560]
  unsigned short* Annb= Xb  + 4*48*2560;      // bf16 ann          [512][1024]
  unsigned short* Pb  = Annb+ 512*1024;       // bf16 probs        [<=176][512]

  // one-time preprocessing
  k_cvt<<<512, 256, 0, stream>>>(ann, Annb, 512*1024);
  k_tr2<<<dim3(32,16), 256, 0, stream>>>(ann, AnT, 512, 1024);
  k_gemm<4><<<dim3(16,8,1), 256, 0, stream>>>(Annb, W_att, 1024, b_att, AHV, 1024, 1024, 512);
  k_root<<<4, 256, 0, stream>>>(rootH, rootC, Hb, Cb, Hbf, XP);

  const int LS[6] = {0,1,5,21,85,256};
  for (int lev=0; lev<5; ++lev){
    int s=LS[lev], e=LS[lev+1], n=e-s;
    if (lev>0){
      k_xasm<<<n,256,0,stream>>>(emb, values, Etb, Hb, Xb, s, e);
      // LSTM gates: split-K (chunk 512, KS=5), z = slot; partials -> PB
      if (lev==4)
        k_gemm_skz<3,16><<<dim3(64,5,4),256,0,stream>>>(Xb, W_ih,1536, W_hh,1024, PB,
            4096, n, 1, 48, 48*2560, 4096*1536, 4096*1024, 5);
      else
        k_gemm_skz<1,16><<<dim3(64,5,4),256,0,stream>>>(Xb, W_ih,1536, W_hh,1024, PB,
            4096, n, 1, 48, 48*2560, 4096*1536, 4096*1024, 5);
      k_epi<<<n,256,0,stream>>>(PB, b_ih, b_hh, Hb, Cb, Hbf, XP, s, e);
    }
    int mtn = (n+15)/16;
    // attention logits: [n x 512] = h · AHV^T  (split-K, fused softmax)
    gemm_sk_part(stream, mtn, Hbf + (size_t)s*1024, AHV, 1024, nullptr,0, Psk, 512, n);
    k_soft<<<n,256,0,stream>>>(Psk, 8, n, Pb);
    // ctx: [n x 1024] = probs · ann
    gemm_sk(stream, mtn, Pb, AnT, 512, nullptr,0, Psk, nullptr, nullptr,
            XP + (size_t)s*2048 + 1024, 2048, 1024, n, 0);
    // et = tanh(W_pre [h|ctx] + b_pre)
    gemm_sk(stream, mtn, XP + (size_t)s*2048, W_pre, 2048, nullptr,0, Psk, b_pre, nullptr,
            Etb + (size_t)s*1024, 1024, 1024, n, 1);
  }

  // W_out logits: split-K KS=4 (chunk 256), MT=16 covers M=256
  k_gemm_skz<16,8><<<dim3(157,4,1),256,0,stream>>>(Etb, W_out,1024, nullptr,0, PB,
      10001, 256, 0, 256, 0,0,0, 4);
  k_red<<<(256*10001+255)/256, 256, 0, stream>>>(PB, 4, 256, 10001, b_out, 0, Lg, nullptr, 10001);
  k_loss <<<256,256,0,stream>>>(Lg, values, Nl);
  k_final<<<1,  256,0,stream>>>(Nl, (float*)d_out);
}

// Round 7
// 464.702 us; speedup vs baseline: 3.4356x; 1.1413x over previous
//
#include <hip/hip_runtime.h>
#include <hip/hip_bf16.h>
#include <math.h>

#define HD 1024
#define NCLS 10001

typedef short s16x8 __attribute__((ext_vector_type(8)));
typedef float f32x4 __attribute__((ext_vector_type(4)));
#define MFMA16(a_, b_, c_) __builtin_amdgcn_mfma_f32_16x16x32_bf16((a_), (b_), (c_), 0, 0, 0)

__device__ __forceinline__ float sigf(float x){ return 1.f/(1.f+__expf(-x)); }
__device__ __forceinline__ float tanhfast(float x){
  x = fminf(fmaxf(x,-10.f),10.f);
  float e2 = __expf(2.f*x);
  return (e2-1.f)/(e2+1.f);
}
__device__ __forceinline__ unsigned short f2bf(float f){
  unsigned int u = __float_as_uint(f);
  u += 0x7FFF + ((u >> 16) & 1);          // round-to-nearest-even
  return (unsigned short)(u >> 16);
}

// ---------------- fp32 -> bf16 bulk convert (flat) ----------------
__global__ __launch_bounds__(256) void k_cvt(const float* __restrict__ A, unsigned short* __restrict__ B, int n){
  int i = (blockIdx.x*256 + threadIdx.x)*4;
  if (i < n){
    float4 v = *(const float4*)(A+i);
    B[i]=f2bf(v.x); B[i+1]=f2bf(v.y); B[i+2]=f2bf(v.z); B[i+3]=f2bf(v.w);
  }
}

// ---------------- build combined LSTM weights: Wb[sr][2560] = [W_ih row (1536) | W_hh row (1024)] bf16 ----------------
__global__ __launch_bounds__(256) void k_cvtw(const float* __restrict__ Wih, const float* __restrict__ Whh,
                                              unsigned short* __restrict__ Wb){
  unsigned e4 = (blockIdx.x*256 + threadIdx.x)*4;         // over 4*4096*2560
  unsigned sr = e4 / 2560;
  unsigned c  = e4 - sr*2560;
  const float* src = (c < 1536) ? (Wih + (size_t)sr*1536 + c) : (Whh + (size_t)sr*1024 + (c-1536));
  float4 v = *(const float4*)src;
  unsigned short* d = Wb + e4;
  d[0]=f2bf(v.x); d[1]=f2bf(v.y); d[2]=f2bf(v.z); d[3]=f2bf(v.w);
}

// ---------------- split W_pre: cols [0,1024) -> Bpre[row][0:1024]; cols [1024,2048) -> Wc[row][:] ----------------
__global__ __launch_bounds__(256) void k_cvtpre(const float* __restrict__ Wpre,
                                                unsigned short* __restrict__ Bpre, unsigned short* __restrict__ Wc){
  unsigned idx4 = (blockIdx.x*256 + threadIdx.x)*4;       // over 1024*2048
  unsigned row = idx4 >> 11, c = idx4 & 2047;
  float4 v = *(const float4*)(Wpre + idx4);
  unsigned short* d = (c < 1024) ? (Bpre + (size_t)row*1536 + c) : (Wc + (size_t)row*1024 + (c-1024));
  d[0]=f2bf(v.x); d[1]=f2bf(v.y); d[2]=f2bf(v.z); d[3]=f2bf(v.w);
}

// ---------------- root state ----------------
__global__ __launch_bounds__(256) void k_root(const float* __restrict__ rH, const float* __restrict__ rC,
                                              float* __restrict__ Hb, float* __restrict__ Cb,
                                              unsigned short* __restrict__ XH){
  int t = blockIdx.x*256 + threadIdx.x;
  if (t < HD){ Hb[t]=rH[t]; Cb[t]=rC[t]; XH[t]=f2bf(rH[t]); }
}

// ---------------- X assembly for LSTM level: X[slot][j] = [emb(values[p]) | Et_bf[p] | h_bf[p]] ----------------
__global__ __launch_bounds__(256) void k_xasm(const float* __restrict__ emb, const int* __restrict__ values,
                                              const unsigned short* __restrict__ Etb, const unsigned short* __restrict__ XH,
                                              unsigned short* __restrict__ X, int s, int e){
  int i = s + blockIdx.x;
  if (i >= e) return;
  int slot = (i - s) & 3, j = (i - s) >> 2;
  int p = (i - 1) >> 2;
  unsigned short* xr = X + ((size_t)slot*48 + j) * 2560;
  int tid = threadIdx.x;
  const float* er = emb + (size_t)values[p] * 512;
  for (int c = tid; c < 512;  c += 256) xr[c]        = f2bf(er[c]);
  const unsigned short* et = Etb + (size_t)p * 1024;
  for (int c = tid; c < 1024; c += 256) xr[512 + c]  = et[c];
  const unsigned short* hp = XH + (size_t)p * 1536;
  for (int c = tid; c < 1024; c += 256) xr[1536 + c] = hp[c];
}

// ---------------- full-K bf16 GEMM: C[m][n] = A[m]·B[n] + bias[n]; row tile via blockIdx.y ----------------
template<int MT>
__global__ __launch_bounds__(256) void k_gemm_fb(
    const unsigned short* __restrict__ A, int astride,
    const unsigned short* __restrict__ B, int K,
    const float* __restrict__ bias,
    float* __restrict__ Cf, unsigned short* __restrict__ Cb16,
    int ostride, int coff, int N, int M)
{
  const int mb0 = blockIdx.y * (MT*16);
  const int wv = threadIdx.x >> 6, lane = threadIdx.x & 63;
  const int col = (blockIdx.x*4 + wv)*16 + (lane & 15);
  const int colc = min(col, N-1);
  const int khalf = (lane >> 4) * 8;

  f32x4 acc[MT];
  #pragma unroll
  for (int m = 0; m < MT; ++m) acc[m] = (f32x4){0.f,0.f,0.f,0.f};
  int arow[MT];
  #pragma unroll
  for (int m = 0; m < MT; ++m) arow[m] = min(mb0 + m*16 + (lane & 15), M-1);

  #pragma unroll 4
  for (int kk = 0; kk < K; kk += 32) {
    int kb = kk + khalf;
    s16x8 bfv = *(const s16x8*)(B + (size_t)colc*K + kb);
    #pragma unroll
    for (int m = 0; m < MT; ++m) {
      s16x8 af = *(const s16x8*)(A + (size_t)arow[m]*astride + kb);
      acc[m] = MFMA16(af, bfv, acc[m]);
    }
  }

  const int r0 = (lane >> 4) * 4;
  #pragma unroll
  for (int m = 0; m < MT; ++m) {
    #pragma unroll
    for (int q = 0; q < 4; ++q) {
      int row = mb0 + m*16 + r0 + q;
      if (row < M && col < N) {
        float v = acc[m][q] + (bias ? bias[col] : 0.f);
        size_t off = (size_t)row*ostride + col + coff;
        if (Cb16) Cb16[off] = f2bf(v); else Cf[off] = v;
      }
    }
  }
}

// ---------------- split-K + slot-batched bf16 GEMM (LSTM): P[((z*KS+ks)*Mpad+row)*N+col] ----------------
template<int MT, int KITER>
__global__ __launch_bounds__(256) void k_gemm_skzb(
    const unsigned short* __restrict__ A,
    const unsigned short* __restrict__ B, int K,
    float* __restrict__ P, int N, int Mbase, int Mpad,
    int aZ, int bZ, int KS)
{
  const int z = blockIdx.z;
  const int M = (Mbase - z + 3) >> 2;
  const unsigned short* Az = A + (size_t)z*aZ;
  const unsigned short* Bz = B + (size_t)z*bZ;
  const int ks = blockIdx.y;
  const int k0 = ks * (KITER*32);
  const int wv = threadIdx.x >> 6, lane = threadIdx.x & 63;
  const int col = (blockIdx.x*4 + wv)*16 + (lane & 15);
  const int colc = min(col, N-1);
  const int khalf = (lane >> 4) * 8;

  f32x4 acc[MT];
  #pragma unroll
  for (int m = 0; m < MT; ++m) acc[m] = (f32x4){0.f,0.f,0.f,0.f};
  int arow[MT];
  #pragma unroll
  for (int m = 0; m < MT; ++m) arow[m] = min(m*16 + (lane & 15), M-1);

  #pragma unroll 4
  for (int kk = 0; kk < KITER*32; kk += 32) {
    int kb = k0 + kk + khalf;
    s16x8 bfv = *(const s16x8*)(Bz + (size_t)colc*K + kb);
    #pragma unroll
    for (int m = 0; m < MT; ++m) {
      s16x8 af = *(const s16x8*)(Az + (size_t)arow[m]*K + kb);
      acc[m] = MFMA16(af, bfv, acc[m]);
    }
  }

  const int r0 = (lane >> 4) * 4;
  #pragma unroll
  for (int m = 0; m < MT; ++m) {
    #pragma unroll
    for (int q = 0; q < 4; ++q) {
      int row = m*16 + r0 + q;
      if (row < M && col < N)
        P[(((size_t)z*KS + ks)*Mpad + row)*N + col] = acc[m][q];
    }
  }
}

// ---------------- small split-K bf16 GEMM (chunk 128): P[ks][M][N] ----------------
template<int MT>
__global__ __launch_bounds__(256) void k_gemm_skb(
    const unsigned short* __restrict__ A, int astride,
    const unsigned short* __restrict__ B, int K,
    float* __restrict__ P, int N, int M)
{
  const int ks = blockIdx.y;
  const int k0 = ks * 128;
  const int wv = threadIdx.x >> 6, lane = threadIdx.x & 63;
  const int col = (blockIdx.x*4 + wv)*16 + (lane & 15);
  const int colc = min(col, N-1);
  const int khalf = (lane >> 4) * 8;

  f32x4 acc[MT];
  #pragma unroll
  for (int m = 0; m < MT; ++m) acc[m] = (f32x4){0.f,0.f,0.f,0.f};
  int arow[MT];
  #pragma unroll
  for (int m = 0; m < MT; ++m) arow[m] = min(m*16 + (lane & 15), M-1);

  #pragma unroll
  for (int kk = 0; kk < 128; kk += 32) {
    int kb = k0 + kk + khalf;
    s16x8 bfv = *(const s16x8*)(B + (size_t)colc*K + kb);
    #pragma unroll
    for (int m = 0; m < MT; ++m) {
      s16x8 af = *(const s16x8*)(A + (size_t)arow[m]*astride + kb);
      acc[m] = MFMA16(af, bfv, acc[m]);
    }
  }

  const int r0 = (lane >> 4) * 4;
  #pragma unroll
  for (int m = 0; m < MT; ++m) {
    #pragma unroll
    for (int q = 0; q < 4; ++q) {
      int row = m*16 + r0 + q;
      if (row < M && col < N)
        P[((size_t)ks*M + row)*N + col] = acc[m][q];
    }
  }
}

// ---------------- split-K reduction ----------------
__global__ __launch_bounds__(256) void k_red(const float* __restrict__ P, int KS, int M, int N,
                                             const float* __restrict__ bias, int tanh_flag,
                                             float* __restrict__ Cf, unsigned short* __restrict__ Cb16,
                                             int ostride)
{
  int idx = blockIdx.x*256 + threadIdx.x;
  if (idx >= M*N) return;
  int row = idx / N, col = idx - row*N;
  float s = bias ? bias[col] : 0.f;
  for (int ks = 0; ks < KS; ++ks) s += P[((size_t)ks*M + row)*N + col];
  if (tanh_flag) s = tanhfast(s);
  if (Cb16) Cb16[(size_t)row*ostride + col] = f2bf(s);
  else      Cf  [(size_t)row*ostride + col] = s;
}

// ---------------- fused split-K sum + softmax over 512 logits -> bf16 probs into XH[.][1024:1536] ----------------
__global__ __launch_bounds__(256) void k_soft(const float* __restrict__ P, int KS, int M,
                                              unsigned short* __restrict__ dst)  // dst = XH + s*1536 + 1024
{
  __shared__ float sm[512];
  __shared__ float red[8];
  const int m = blockIdx.x;
  const int tid = threadIdx.x, wv = tid>>6, ln = tid&63;
  for (int l = tid; l < 512; l += 256) {
    float s = 0.f;
    for (int ks = 0; ks < KS; ++ks) s += P[((size_t)ks*M + m)*512 + l];
    sm[l] = s;
  }
  __syncthreads();
  float mx = -1e30f;
  for (int l=tid; l<512; l+=256) mx = fmaxf(mx, sm[l]);
  #pragma unroll
  for (int o=32;o;o>>=1) mx = fmaxf(mx, __shfl_xor(mx,o,64));
  if (ln==0) red[wv]=mx;
  __syncthreads();
  mx = fmaxf(fmaxf(red[0],red[1]),fmaxf(red[2],red[3]));
  float se = 0.f;
  for (int l=tid; l<512; l+=256){ float ev=__expf(sm[l]-mx); sm[l]=ev; se+=ev; }
  __syncthreads();
  #pragma unroll
  for (int o=32;o;o>>=1) se += __shfl_xor(se,o,64);
  if (ln==0) red[wv]=se;
  __syncthreads();
  float invS = 1.f/(red[0]+red[1]+red[2]+red[3]);
  for (int l=tid; l<512; l+=256) dst[(size_t)m*1536 + l] = f2bf(sm[l]*invS);
}

// ---------------- LSTM epilogue (sums KS=5 gate partials + biases) ----------------
__global__ __launch_bounds__(256) void k_epi(const float* __restrict__ P,
                                             const float* __restrict__ b_ih, const float* __restrict__ b_hh,
                                             float* __restrict__ Hb, float* __restrict__ Cb,
                                             unsigned short* __restrict__ XH, int s, int e){
  int i = s + blockIdx.x;
  if (i >= e) return;
  int slot = (i - s) & 3, j = (i - s) >> 2;
  int p = (i - 1) >> 2;
  const float* bi = b_ih + (size_t)slot*4096;
  const float* bh = b_hh + (size_t)slot*4096;
  for (int u = threadIdx.x; u < 1024; u += 256) {
    float ig = bi[u]      + bh[u];
    float fg = bi[1024+u] + bh[1024+u];
    float gg = bi[2048+u] + bh[2048+u];
    float og = bi[3072+u] + bh[3072+u];
    #pragma unroll
    for (int ks = 0; ks < 5; ++ks) {
      const float* g = P + (((size_t)slot*5 + ks)*48 + j)*4096;
      ig += g[u]; fg += g[1024+u]; gg += g[2048+u]; og += g[3072+u];
    }
    float cp = Cb[(size_t)p*1024 + u];
    float c  = sigf(fg)*cp + sigf(ig)*tanhfast(gg);
    float h  = sigf(og)*tanhfast(c);
    Hb[(size_t)i*1024+u] = h;
    Cb[(size_t)i*1024+u] = c;
    XH[(size_t)i*1536+u] = f2bf(h);
  }
}

// ---------------- loss per node ----------------
__global__ __launch_bounds__(256) void k_loss(const float* __restrict__ Lg,
                                              const int* __restrict__ values,
                                              float* __restrict__ Nl)
{
  __shared__ float red[8];
  const int node = blockIdx.x;
  const int tid = threadIdx.x, wv = tid>>6, ln = tid&63;
  const float* lg = Lg + (size_t)node*NCLS;

  float m = -1e30f;
  for (int i=tid;i<NCLS;i+=256) m = fmaxf(m, lg[i]);
  #pragma unroll
  for (int o=32;o;o>>=1) m = fmaxf(m, __shfl_xor(m,o,64));
  if (ln==0) red[wv]=m;
  __syncthreads();
  m = fmaxf(fmaxf(red[0],red[1]),fmaxf(red[2],red[3]));
  __syncthreads();

  float s = 0.f;
  for (int i=tid;i<NCLS;i+=256) s += __expf(lg[i]-m);
  #pragma unroll
  for (int o=32;o;o>>=1) s += __shfl_xor(s,o,64);
  if (ln==0) red[wv]=s;
  __syncthreads();
  s = red[0]+red[1]+red[2]+red[3];
  __syncthreads();
  float invs = 1.f/s;

  float q = 0.f;
  for (int i=tid;i<NCLS;i+=256) q += __expf(__expf(lg[i]-m)*invs);
  #pragma unroll
  for (int o=32;o;o>>=1) q += __shfl_xor(q,o,64);
  if (ln==0) red[wv]=q;
  __syncthreads();
  if (tid==0) {
    float qq = red[0]+red[1]+red[2]+red[3];
    int v = values[node];
    float pv = __expf(lg[v]-m)*invs;
    float nl = __logf(qq) - pv;
    if (v == NCLS-1) nl *= 0.2f;
    Nl[node] = nl;
  }
}

__global__ __launch_bounds__(256) void k_final(const float* __restrict__ Nl, float* __restrict__ out){
  __shared__ float red[8];
  int tid = threadIdx.x, wv = tid>>6, ln = tid&63;
  float s = Nl[tid];
  #pragma unroll
  for (int o=32;o;o>>=1) s += __shfl_xor(s,o,64);
  if (ln==0) red[wv]=s;
  __syncthreads();
  if (tid==0) out[0] = red[0]+red[1]+red[2]+red[3];
}

static inline void gemm_skb(hipStream_t st, int MT, const unsigned short* A, int astride,
                            const unsigned short* B, int K, float* P, int N, int M)
{
  dim3 grid(N/64, K/128);
  #define SKCASE(MTv) k_gemm_skb<MTv><<<grid, 256, 0, st>>>(A,astride,B,K,P,N,M)
  switch(MT){
    case 1:  SKCASE(1);  break;
    case 4:  SKCASE(4);  break;
    case 11: SKCASE(11); break;
    default: SKCASE(16); break;
  }
  #undef SKCASE
}

extern "C" void kernel_launch(void* const* d_in, const int* in_sizes, int n_in,
                              void* d_out, int out_size, void* d_ws, size_t ws_size,
                              hipStream_t stream)
{
  const float* rootH = (const float*)d_in[0];
  const float* rootC = (const float*)d_in[1];
  const float* ann   = (const float*)d_in[2];
  const int*   values= (const int*)d_in[3];
  const float* emb   = (const float*)d_in[6];
  const float* W_ih  = (const float*)d_in[7];
  const float* W_hh  = (const float*)d_in[8];
  const float* b_ih  = (const float*)d_in[9];
  const float* b_hh  = (const float*)d_in[10];
  const float* W_att = (const float*)d_in[11];
  const float* b_att = (const float*)d_in[12];
  const float* W_pre = (const float*)d_in[13];
  const float* b_pre = (const float*)d_in[14];
  const float* W_out = (const float*)d_in[15];
  const float* b_out = (const float*)d_in[16];

  float* ws = (float*)d_ws;
  float* Hb  = ws; ws += 256*1024;              // fp32 h
  float* Cb  = ws; ws += 256*1024;              // fp32 c
  float* Lg  = ws; ws += (size_t)256*NCLS;      // fp32 logits
  float* Nl  = ws; ws += 256;
  float* PB  = ws; ws += 4*5*48*4096;           // shared split-K partials (LSTM 15.7MB > logits 2.9 > pre 2.2)
  unsigned short* Wb    = (unsigned short*)ws;  // bf16 [4][4096][2560] combined LSTM weights
  unsigned short* Woutb = Wb    + (size_t)4*4096*2560;   // bf16 [10001][1024]
  unsigned short* Wattb = Woutb + (size_t)NCLS*1024;     // bf16 [1024][1024]
  unsigned short* Bpre  = Wattb + 1024*1024;    // bf16 [1024][1536] = [W_pre_h | ANWT]
  unsigned short* Wpcb  = Bpre  + 1024*1536;    // bf16 [1024][1024] W_pre ctx half
  unsigned short* AHVb  = Wpcb  + 1024*1024;    // bf16 [512][1024]
  unsigned short* Annb  = AHVb  + 512*1024;     // bf16 [512][1024]
  unsigned short* XH    = Annb  + 512*1024;     // bf16 [256][1536] = [h | probs]
  unsigned short* Etb   = XH    + 256*1536;     // bf16 [256][1024]
  unsigned short* Xb    = Etb   + 256*1024;     // bf16 [4][48][2560]

  // ---- one-time conversions ----
  k_cvt  <<<512,   256, 0, stream>>>(ann,   Annb,  512*1024);
  k_cvt  <<<1024,  256, 0, stream>>>(W_att, Wattb, 1024*1024);
  k_cvt  <<<NCLS,  256, 0, stream>>>(W_out, Woutb, NCLS*1024);
  k_cvtw <<<40960, 256, 0, stream>>>(W_ih, W_hh, Wb);
  k_cvtpre<<<2048, 256, 0, stream>>>(W_pre, Bpre, Wpcb);
  // AHV = ann @ W_att^T + b_att  (bf16 out)
  k_gemm_fb<4><<<dim3(16,8),  256, 0, stream>>>(Annb, 1024, Wattb, 1024, b_att, nullptr, AHVb, 1024, 0, 1024, 512);
  // ANWT[out][l] = W_pre_ctx[out]·ann[l]  -> Bpre[out][1024:1536]
  k_gemm_fb<4><<<dim3(8,16),  256, 0, stream>>>(Wpcb, 1024, Annb, 1024, nullptr, nullptr, Bpre, 1536, 1024, 512, 1024);
  k_root<<<4, 256, 0, stream>>>(rootH, rootC, Hb, Cb, XH);

  const int LS[6] = {0,1,5,21,85,256};
  for (int lev=0; lev<5; ++lev){
    int s=LS[lev], e=LS[lev+1], n=e-s;
    if (lev>0){
      k_xasm<<<n,256,0,stream>>>(emb, values, Etb, XH, Xb, s, e);
      if (lev==4)
        k_gemm_skzb<3,16><<<dim3(64,5,4),256,0,stream>>>(Xb, Wb, 2560, PB, 4096, n, 48, 48*2560, 4096*2560, 5);
      else
        k_gemm_skzb<1,16><<<dim3(64,5,4),256,0,stream>>>(Xb, Wb, 2560, PB, 4096, n, 48, 48*2560, 4096*2560, 5);
      k_epi<<<n,256,0,stream>>>(PB, b_ih, b_hh, Hb, Cb, XH, s, e);
    }
    int mtn = (n+15)/16;
    // attention logits [n x 512] = h · AHV^T (split-K) + fused softmax -> probs into XH[.][1024:1536]
    gemm_skb(stream, mtn, XH + (size_t)s*1536, 1536, AHVb, 1024, PB, 512, n);
    k_soft<<<n,256,0,stream>>>(PB, 8, n, XH + (size_t)s*1536 + 1024);
    // et = tanh([h|probs] · Bpre^T + b_pre)   (ctx GEMM algebraically folded into Bpre)
    gemm_skb(stream, mtn, XH + (size_t)s*1536, 1536, Bpre, 1536, PB, 1024, n);
    k_red<<<(n*1024+255)/256, 256, 0, stream>>>(PB, 12, n, 1024, b_pre, 1, nullptr, Etb + (size_t)s*1024, 1024);
  }

  // W_out logits: full-K bf16, 4 row tiles
  k_gemm_fb<4><<<dim3(157,4), 256, 0, stream>>>(Etb, 1024, Woutb, 1024, b_out, Lg, nullptr, NCLS, 0, NCLS, 256);
  k_loss <<<256,256,0,stream>>>(Lg, values, Nl);
  k_final<<<1,  256,0,stream>>>(Nl, (float*)d_out);
}

// Round 8
// 449.305 us; speedup vs baseline: 3.5533x; 1.0343x over previous
//
#include <hip/hip_runtime.h>
#include <hip/hip_bf16.h>
#include <math.h>

#define HD 1024
#define NCLS 10001

typedef short s16x8 __attribute__((ext_vector_type(8)));
typedef unsigned short u16x8 __attribute__((ext_vector_type(8)));
typedef float f32x4 __attribute__((ext_vector_type(4)));
#define MFMA16(a_, b_, c_) __builtin_amdgcn_mfma_f32_16x16x32_bf16((a_), (b_), (c_), 0, 0, 0)

__device__ __forceinline__ float sigf(float x){ return 1.f/(1.f+__expf(-x)); }
__device__ __forceinline__ float tanhfast(float x){
  x = fminf(fmaxf(x,-10.f),10.f);
  float e2 = __expf(2.f*x);
  return (e2-1.f)/(e2+1.f);
}
__device__ __forceinline__ unsigned short f2bf(float f){
  unsigned int u = __float_as_uint(f);
  u += 0x7FFF + ((u >> 16) & 1);          // round-to-nearest-even
  return (unsigned short)(u >> 16);
}
__device__ __forceinline__ u16x8 pack8(float4 a, float4 b){
  u16x8 r;
  r[0]=f2bf(a.x); r[1]=f2bf(a.y); r[2]=f2bf(a.z); r[3]=f2bf(a.w);
  r[4]=f2bf(b.x); r[5]=f2bf(b.y); r[6]=f2bf(b.z); r[7]=f2bf(b.w);
  return r;
}

// ---------------- fp32 -> bf16 bulk convert, 8 elems/thread, 16B stores ----------------
__global__ __launch_bounds__(256) void k_cvt8(const float* __restrict__ A, unsigned short* __restrict__ B, int n){
  int i = (blockIdx.x*256 + threadIdx.x)*8;
  if (i < n){
    float4 a = *(const float4*)(A+i);
    float4 b = *(const float4*)(A+i+4);
    *(u16x8*)(B+i) = pack8(a,b);
  }
}

// ---------------- combined LSTM weights: Wb[sr][2560] = [W_ih row (1536) | W_hh row (1024)] bf16 ----------------
__global__ __launch_bounds__(256) void k_cvtw8(const float* __restrict__ Wih, const float* __restrict__ Whh,
                                               unsigned short* __restrict__ Wb){
  unsigned e8 = (blockIdx.x*256 + threadIdx.x)*8;         // over 4*4096*2560 (mult of 8)
  unsigned sr = e8 / 2560;
  unsigned c  = e8 - sr*2560;
  const float* src = (c < 1536) ? (Wih + (size_t)sr*1536 + c) : (Whh + (size_t)sr*1024 + (c-1536));
  float4 a = *(const float4*)src;
  float4 b = *(const float4*)(src+4);
  *(u16x8*)(Wb + e8) = pack8(a,b);
}

// ---------------- split W_pre: cols [0,1024) -> Bpre[row][0:1024]; cols [1024,2048) -> Wc ----------------
__global__ __launch_bounds__(256) void k_cvtpre8(const float* __restrict__ Wpre,
                                                 unsigned short* __restrict__ Bpre, unsigned short* __restrict__ Wc){
  unsigned idx8 = (blockIdx.x*256 + threadIdx.x)*8;       // over 1024*2048
  unsigned row = idx8 >> 11, c = idx8 & 2047;
  float4 a = *(const float4*)(Wpre + idx8);
  float4 b = *(const float4*)(Wpre + idx8 + 4);
  unsigned short* d = (c < 1024) ? (Bpre + (size_t)row*1536 + c) : (Wc + (size_t)row*1024 + (c-1024));
  *(u16x8*)d = pack8(a,b);
}

// ---------------- root state ----------------
__global__ __launch_bounds__(256) void k_root(const float* __restrict__ rH, const float* __restrict__ rC,
                                              float* __restrict__ Hb, float* __restrict__ Cb,
                                              unsigned short* __restrict__ XH){
  int t = blockIdx.x*256 + threadIdx.x;
  if (t < HD){ Hb[t]=rH[t]; Cb[t]=rC[t]; XH[t]=f2bf(rH[t]); }
}

// ---------------- X assembly for LSTM level: X[slot][j] = [emb(values[p]) | Et_bf[p] | h_bf[p]] ----------------
__global__ __launch_bounds__(256) void k_xasm(const float* __restrict__ emb, const int* __restrict__ values,
                                              const unsigned short* __restrict__ Etb, const unsigned short* __restrict__ XH,
                                              unsigned short* __restrict__ X, int s, int e){
  int i = s + blockIdx.x;
  if (i >= e) return;
  int slot = (i - s) & 3, j = (i - s) >> 2;
  int p = (i - 1) >> 2;
  unsigned short* xr = X + ((size_t)slot*48 + j) * 2560;
  int tid = threadIdx.x;
  const float* er = emb + (size_t)values[p] * 512;
  if (tid < 64) {   // 512 elems, 8/thread
    int c = tid*8;
    float4 a = *(const float4*)(er+c);
    float4 b = *(const float4*)(er+c+4);
    *(u16x8*)(xr+c) = pack8(a,b);
  }
  const unsigned short* et = Etb + (size_t)p * 1024;
  for (int c = tid*4; c < 1024*4; c += 256*4) {} // (no-op placeholder removed below)
  for (int c = tid; c < 256; c += 256) {
    ((u16x8*)(xr+512))[c]  = ((const u16x8*)et)[c];
  }
  const unsigned short* hp = XH + (size_t)p * 1536;
  for (int c = tid; c < 128; c += 256) {
    ((u16x8*)(xr+1536))[c] = ((const u16x8*)hp)[c];
  }
  if (tid >= 128 && tid < 256) {
    int c = tid - 128;
    ((u16x8*)(xr+1536))[c+0] = ((const u16x8*)hp)[c+0];
  }
}

// ---------------- full-K bf16 GEMM: C[m][n] = A[m]·B[n] + bias[n]; row tile via blockIdx.y ----------------
template<int MT>
__global__ __launch_bounds__(256) void k_gemm_fb(
    const unsigned short* __restrict__ A, int astride,
    const unsigned short* __restrict__ B, int K,
    const float* __restrict__ bias,
    float* __restrict__ Cf, unsigned short* __restrict__ Cb16,
    int ostride, int coff, int N, int M)
{
  const int mb0 = blockIdx.y * (MT*16);
  const int wv = threadIdx.x >> 6, lane = threadIdx.x & 63;
  const int col = (blockIdx.x*4 + wv)*16 + (lane & 15);
  const int colc = min(col, N-1);
  const int khalf = (lane >> 4) * 8;

  f32x4 acc[MT];
  #pragma unroll
  for (int m = 0; m < MT; ++m) acc[m] = (f32x4){0.f,0.f,0.f,0.f};
  int arow[MT];
  #pragma unroll
  for (int m = 0; m < MT; ++m) arow[m] = min(mb0 + m*16 + (lane & 15), M-1);

  #pragma unroll 4
  for (int kk = 0; kk < K; kk += 32) {
    int kb = kk + khalf;
    s16x8 bfv = *(const s16x8*)(B + (size_t)colc*K + kb);
    #pragma unroll
    for (int m = 0; m < MT; ++m) {
      s16x8 af = *(const s16x8*)(A + (size_t)arow[m]*astride + kb);
      acc[m] = MFMA16(af, bfv, acc[m]);
    }
  }

  const int r0 = (lane >> 4) * 4;
  #pragma unroll
  for (int m = 0; m < MT; ++m) {
    #pragma unroll
    for (int q = 0; q < 4; ++q) {
      int row = mb0 + m*16 + r0 + q;
      if (row < M && col < N) {
        float v = acc[m][q] + (bias ? bias[col] : 0.f);
        size_t off = (size_t)row*ostride + col + coff;
        if (Cb16) Cb16[off] = f2bf(v); else Cf[off] = v;
      }
    }
  }
}

// ---------------- split-K + slot-batched bf16 GEMM (LSTM): P[((z*KS+ks)*Mpad+row)*N+col] ----------------
template<int MT, int KITER>
__global__ __launch_bounds__(256) void k_gemm_skzb(
    const unsigned short* __restrict__ A,
    const unsigned short* __restrict__ B, int K,
    float* __restrict__ P, int N, int Mbase, int Mpad,
    int aZ, int bZ, int KS)
{
  const int z = blockIdx.z;
  const int M = (Mbase - z + 3) >> 2;
  const unsigned short* Az = A + (size_t)z*aZ;
  const unsigned short* Bz = B + (size_t)z*bZ;
  const int ks = blockIdx.y;
  const int k0 = ks * (KITER*32);
  const int wv = threadIdx.x >> 6, lane = threadIdx.x & 63;
  const int col = (blockIdx.x*4 + wv)*16 + (lane & 15);
  const int colc = min(col, N-1);
  const int khalf = (lane >> 4) * 8;

  f32x4 acc[MT];
  #pragma unroll
  for (int m = 0; m < MT; ++m) acc[m] = (f32x4){0.f,0.f,0.f,0.f};
  int arow[MT];
  #pragma unroll
  for (int m = 0; m < MT; ++m) arow[m] = min(m*16 + (lane & 15), M-1);

  #pragma unroll 4
  for (int kk = 0; kk < KITER*32; kk += 32) {
    int kb = k0 + kk + khalf;
    s16x8 bfv = *(const s16x8*)(Bz + (size_t)colc*K + kb);
    #pragma unroll
    for (int m = 0; m < MT; ++m) {
      s16x8 af = *(const s16x8*)(Az + (size_t)arow[m]*K + kb);
      acc[m] = MFMA16(af, bfv, acc[m]);
    }
  }

  const int r0 = (lane >> 4) * 4;
  #pragma unroll
  for (int m = 0; m < MT; ++m) {
    #pragma unroll
    for (int q = 0; q < 4; ++q) {
      int row = m*16 + r0 + q;
      if (row < M && col < N)
        P[(((size_t)z*KS + ks)*Mpad + row)*N + col] = acc[m][q];
    }
  }
}

// ---------------- small split-K bf16 GEMM (chunk 128): P[ks][M][N] ----------------
template<int MT>
__global__ __launch_bounds__(256) void k_gemm_skb(
    const unsigned short* __restrict__ A, int astride,
    const unsigned short* __restrict__ B, int K,
    float* __restrict__ P, int N, int M)
{
  const int ks = blockIdx.y;
  const int k0 = ks * 128;
  const int wv = threadIdx.x >> 6, lane = threadIdx.x & 63;
  const int col = (blockIdx.x*4 + wv)*16 + (lane & 15);
  const int colc = min(col, N-1);
  const int khalf = (lane >> 4) * 8;

  f32x4 acc[MT];
  #pragma unroll
  for (int m = 0; m < MT; ++m) acc[m] = (f32x4){0.f,0.f,0.f,0.f};
  int arow[MT];
  #pragma unroll
  for (int m = 0; m < MT; ++m) arow[m] = min(m*16 + (lane & 15), M-1);

  #pragma unroll
  for (int kk = 0; kk < 128; kk += 32) {
    int kb = k0 + kk + khalf;
    s16x8 bfv = *(const s16x8*)(B + (size_t)colc*K + kb);
    #pragma unroll
    for (int m = 0; m < MT; ++m) {
      s16x8 af = *(const s16x8*)(A + (size_t)arow[m]*astride + kb);
      acc[m] = MFMA16(af, bfv, acc[m]);
    }
  }

  const int r0 = (lane >> 4) * 4;
  #pragma unroll
  for (int m = 0; m < MT; ++m) {
    #pragma unroll
    for (int q = 0; q < 4; ++q) {
      int row = m*16 + r0 + q;
      if (row < M && col < N)
        P[((size_t)ks*M + row)*N + col] = acc[m][q];
    }
  }
}

// ---------------- split-K reduction ----------------
__global__ __launch_bounds__(256) void k_red(const float* __restrict__ P, int KS, int M, int N,
                                             const float* __restrict__ bias, int tanh_flag,
                                             float* __restrict__ Cf, unsigned short* __restrict__ Cb16,
                                             int ostride)
{
  int idx = blockIdx.x*256 + threadIdx.x;
  if (idx >= M*N) return;
  int row = idx / N, col = idx - row*N;
  float s = bias ? bias[col] : 0.f;
  for (int ks = 0; ks < KS; ++ks) s += P[((size_t)ks*M + row)*N + col];
  if (tanh_flag) s = tanhfast(s);
  if (Cb16) Cb16[(size_t)row*ostride + col] = f2bf(s);
  else      Cf  [(size_t)row*ostride + col] = s;
}

// ---------------- fused split-K sum + softmax over 512 logits -> bf16 probs into XH[.][1024:1536] ----------------
__global__ __launch_bounds__(256) void k_soft(const float* __restrict__ P, int KS, int M,
                                              unsigned short* __restrict__ dst)
{
  __shared__ float sm[512];
  __shared__ float red[8];
  const int m = blockIdx.x;
  const int tid = threadIdx.x, wv = tid>>6, ln = tid&63;
  for (int l = tid; l < 512; l += 256) {
    float s = 0.f;
    for (int ks = 0; ks < KS; ++ks) s += P[((size_t)ks*M + m)*512 + l];
    sm[l] = s;
  }
  __syncthreads();
  float mx = -1e30f;
  for (int l=tid; l<512; l+=256) mx = fmaxf(mx, sm[l]);
  #pragma unroll
  for (int o=32;o;o>>=1) mx = fmaxf(mx, __shfl_xor(mx,o,64));
  if (ln==0) red[wv]=mx;
  __syncthreads();
  mx = fmaxf(fmaxf(red[0],red[1]),fmaxf(red[2],red[3]));
  float se = 0.f;
  for (int l=tid; l<512; l+=256){ float ev=__expf(sm[l]-mx); sm[l]=ev; se+=ev; }
  __syncthreads();
  #pragma unroll
  for (int o=32;o;o>>=1) se += __shfl_xor(se,o,64);
  if (ln==0) red[wv]=se;
  __syncthreads();
  float invS = 1.f/(red[0]+red[1]+red[2]+red[3]);
  for (int l=tid; l<512; l+=256) dst[(size_t)m*1536 + l] = f2bf(sm[l]*invS);
}

// ---------------- LSTM epilogue (sums KS=5 gate partials + biases) ----------------
__global__ __launch_bounds__(256) void k_epi(const float* __restrict__ P,
                                             const float* __restrict__ b_ih, const float* __restrict__ b_hh,
                                             float* __restrict__ Hb, float* __restrict__ Cb,
                                             unsigned short* __restrict__ XH, int s, int e){
  int i = s + blockIdx.x;
  if (i >= e) return;
  int slot = (i - s) & 3, j = (i - s) >> 2;
  int p = (i - 1) >> 2;
  const float* bi = b_ih + (size_t)slot*4096;
  const float* bh = b_hh + (size_t)slot*4096;
  for (int u = threadIdx.x; u < 1024; u += 256) {
    float ig = bi[u]      + bh[u];
    float fg = bi[1024+u] + bh[1024+u];
    float gg = bi[2048+u] + bh[2048+u];
    float og = bi[3072+u] + bh[3072+u];
    #pragma unroll
    for (int ks = 0; ks < 5; ++ks) {
      const float* g = P + (((size_t)slot*5 + ks)*48 + j)*4096;
      ig += g[u]; fg += g[1024+u]; gg += g[2048+u]; og += g[3072+u];
    }
    float cp = Cb[(size_t)p*1024 + u];
    float c  = sigf(fg)*cp + sigf(ig)*tanhfast(gg);
    float h  = sigf(og)*tanhfast(c);
    Hb[(size_t)i*1024+u] = h;
    Cb[(size_t)i*1024+u] = c;
    XH[(size_t)i*1536+u] = f2bf(h);
  }
}

// ---------------- loss per node ----------------
__global__ __launch_bounds__(256) void k_loss(const float* __restrict__ Lg,
                                              const int* __restrict__ values,
                                              float* __restrict__ Nl)
{
  __shared__ float red[8];
  const int node = blockIdx.x;
  const int tid = threadIdx.x, wv = tid>>6, ln = tid&63;
  const float* lg = Lg + (size_t)node*NCLS;

  float m = -1e30f;
  for (int i=tid;i<NCLS;i+=256) m = fmaxf(m, lg[i]);
  #pragma unroll
  for (int o=32;o;o>>=1) m = fmaxf(m, __shfl_xor(m,o,64));
  if (ln==0) red[wv]=m;
  __syncthreads();
  m = fmaxf(fmaxf(red[0],red[1]),fmaxf(red[2],red[3]));
  __syncthreads();

  float s = 0.f;
  for (int i=tid;i<NCLS;i+=256) s += __expf(lg[i]-m);
  #pragma unroll
  for (int o=32;o;o>>=1) s += __shfl_xor(s,o,64);
  if (ln==0) red[wv]=s;
  __syncthreads();
  s = red[0]+red[1]+red[2]+red[3];
  __syncthreads();
  float invs = 1.f/s;

  float q = 0.f;
  for (int i=tid;i<NCLS;i+=256) q += __expf(__expf(lg[i]-m)*invs);
  #pragma unroll
  for (int o=32;o;o>>=1) q += __shfl_xor(q,o,64);
  if (ln==0) red[wv]=q;
  __syncthreads();
  if (tid==0) {
    float qq = red[0]+red[1]+red[2]+red[3];
    int v = values[node];
    float pv = __expf(lg[v]-m)*invs;
    float nl = __logf(qq) - pv;
    if (v == NCLS-1) nl *= 0.2f;
    Nl[node] = nl;
  }
}

__global__ __launch_bounds__(256) void k_final(const float* __restrict__ Nl, float* __restrict__ out){
  __shared__ float red[8];
  int tid = threadIdx.x, wv = tid>>6, ln = tid&63;
  float s = Nl[tid];
  #pragma unroll
  for (int o=32;o;o>>=1) s += __shfl_xor(s,o,64);
  if (ln==0) red[wv]=s;
  __syncthreads();
  if (tid==0) out[0] = red[0]+red[1]+red[2]+red[3];
}

static inline void gemm_skb(hipStream_t st, int MT, const unsigned short* A, int astride,
                            const unsigned short* B, int K, float* P, int N, int M)
{
  dim3 grid(N/64, K/128);
  #define SKCASE(MTv) k_gemm_skb<MTv><<<grid, 256, 0, st>>>(A,astride,B,K,P,N,M)
  switch(MT){
    case 1:  SKCASE(1);  break;
    case 4:  SKCASE(4);  break;
    case 11: SKCASE(11); break;
    default: SKCASE(16); break;
  }
  #undef SKCASE
}

extern "C" void kernel_launch(void* const* d_in, const int* in_sizes, int n_in,
                              void* d_out, int out_size, void* d_ws, size_t ws_size,
                              hipStream_t stream)
{
  const float* rootH = (const float*)d_in[0];
  const float* rootC = (const float*)d_in[1];
  const float* ann   = (const float*)d_in[2];
  const int*   values= (const int*)d_in[3];
  const float* emb   = (const float*)d_in[6];
  const float* W_ih  = (const float*)d_in[7];
  const float* W_hh  = (const float*)d_in[8];
  const float* b_ih  = (const float*)d_in[9];
  const float* b_hh  = (const float*)d_in[10];
  const float* W_att = (const float*)d_in[11];
  const float* b_att = (const float*)d_in[12];
  const float* W_pre = (const float*)d_in[13];
  const float* b_pre = (const float*)d_in[14];
  const float* W_out = (const float*)d_in[15];
  const float* b_out = (const float*)d_in[16];

  float* ws = (float*)d_ws;
  float* Hb  = ws; ws += 256*1024;              // fp32 h
  float* Cb  = ws; ws += 256*1024;              // fp32 c
  float* Lg  = ws; ws += (size_t)256*NCLS;      // fp32 logits
  float* Nl  = ws; ws += 256;
  float* PB  = ws; ws += 4*5*48*4096;           // shared split-K partials
  unsigned short* Wb    = (unsigned short*)ws;  // bf16 [4][4096][2560] combined LSTM weights
  unsigned short* Woutb = Wb    + (size_t)4*4096*2560;   // bf16 [10001][1024]
  unsigned short* Wattb = Woutb + (size_t)NCLS*1024;     // bf16 [1024][1024]
  unsigned short* Bpre  = Wattb + 1024*1024;    // bf16 [1024][1536] = [W_pre_h | ANWT]
  unsigned short* Wpcb  = Bpre  + 1024*1536;    // bf16 [1024][1024] W_pre ctx half
  unsigned short* AHVb  = Wpcb  + 1024*1024;    // bf16 [512][1024]
  unsigned short* Annb  = AHVb  + 512*1024;     // bf16 [512][1024]
  unsigned short* XH    = Annb  + 512*1024;     // bf16 [256][1536] = [h | probs]
  unsigned short* Etb   = XH    + 256*1536;     // bf16 [256][1024]
  unsigned short* Xb    = Etb   + 256*1024;     // bf16 [4][48][2560]

  // ---- one-time conversions (8 elems/thread, 16B stores) ----
  k_cvt8  <<<256,   256, 0, stream>>>(ann,   Annb,  512*1024);
  k_cvt8  <<<512,   256, 0, stream>>>(W_att, Wattb, 1024*1024);
  k_cvt8  <<<5001,  256, 0, stream>>>(W_out, Woutb, NCLS*1024);
  k_cvtw8 <<<20480, 256, 0, stream>>>(W_ih, W_hh, Wb);
  k_cvtpre8<<<1024, 256, 0, stream>>>(W_pre, Bpre, Wpcb);
  // AHV = ann @ W_att^T + b_att  (bf16 out)
  k_gemm_fb<4><<<dim3(16,8),  256, 0, stream>>>(Annb, 1024, Wattb, 1024, b_att, nullptr, AHVb, 1024, 0, 1024, 512);
  // ANWT[out][l] = W_pre_ctx[out]·ann[l]  -> Bpre[out][1024:1536]
  k_gemm_fb<4><<<dim3(8,16),  256, 0, stream>>>(Wpcb, 1024, Annb, 1024, nullptr, nullptr, Bpre, 1536, 1024, 512, 1024);
  k_root<<<4, 256, 0, stream>>>(rootH, rootC, Hb, Cb, XH);

  const int LS[6] = {0,1,5,21,85,256};
  for (int lev=0; lev<5; ++lev){
    int s=LS[lev], e=LS[lev+1], n=e-s;
    if (lev>0){
      k_xasm<<<n,256,0,stream>>>(emb, values, Etb, XH, Xb, s, e);
      if (lev==4)
        k_gemm_skzb<3,16><<<dim3(64,5,4),256,0,stream>>>(Xb, Wb, 2560, PB, 4096, n, 48, 48*2560, 4096*2560, 5);
      else
        k_gemm_skzb<1,16><<<dim3(64,5,4),256,0,stream>>>(Xb, Wb, 2560, PB, 4096, n, 48, 48*2560, 4096*2560, 5);
      k_epi<<<n,256,0,stream>>>(PB, b_ih, b_hh, Hb, Cb, XH, s, e);
    }
    int mtn = (n+15)/16;
    // attention logits [n x 512] = h · AHV^T (split-K) + fused softmax -> probs into XH[.][1024:1536]
    gemm_skb(stream, mtn, XH + (size_t)s*1536, 1536, AHVb, 1024, PB, 512, n);
    k_soft<<<n,256,0,stream>>>(PB, 8, n, XH + (size_t)s*1536 + 1024);
    // et = tanh([h|probs] · Bpre^T + b_pre)   (ctx GEMM folded into Bpre)
    gemm_skb(stream, mtn, XH + (size_t)s*1536, 1536, Bpre, 1536, PB, 1024, n);
    k_red<<<(n*1024+255)/256, 256, 0, stream>>>(PB, 12, n, 1024, b_pre, 1, nullptr, Etb + (size_t)s*1024, 1024);
  }

  // W_out logits: full-K bf16, 4 row tiles
  k_gemm_fb<4><<<dim3(157,4), 256, 0, stream>>>(Etb, 1024, Woutb, 1024, b_out, Lg, nullptr, NCLS, 0, NCLS, 256);
  k_loss <<<256,256,0,stream>>>(Lg, values, Nl);
  k_final<<<1,  256,0,stream>>>(Nl, (float*)d_out);
}